// Round 1
// baseline (1595.849 us; speedup 1.0000x reference)
//
#include <hip/hip_runtime.h>

// Problem constants
#define B_SZ 4096
#define NHID_ 2048
#define NBO_ 8
#define BSO_ 256
#define NINP_ 512

__device__ __forceinline__ float sigmoidf_(float x) { return 1.f / (1.f + expf(-x)); }

// ---------------------------------------------------------------------------
// Generic fp32 tiled GEMM: C[m,n] = sum_k A[m,k]*B[k,n], batched over z.
// M,N,K must be multiples of 64/64/16 (all call sites satisfy this).
// ---------------------------------------------------------------------------
#define GM_BM 64
#define GM_BN 64
#define GM_BK 16

__global__ __launch_bounds__(256) void gemm_nn(
    const float* __restrict__ A, const float* __restrict__ Bm, float* __restrict__ C,
    int M, int N, int K, int lda, int ldb, int ldc,
    long sA, long sB, long sC)
{
    const int z = blockIdx.z;
    A += (long)z * sA; Bm += (long)z * sB; C += (long)z * sC;
    const int m0 = blockIdx.y * GM_BM;
    const int n0 = blockIdx.x * GM_BN;
    const int tid = threadIdx.x;
    const int tx = tid & 15;
    const int ty = tid >> 4;

    __shared__ float As[GM_BK][GM_BM + 4];
    __shared__ float Bs[GM_BK][GM_BN + 4];

    float acc[4][4] = {};

    for (int k0 = 0; k0 < K; k0 += GM_BK) {
#pragma unroll
        for (int i = 0; i < 4; ++i) {
            int idx = tid + i * 256;
            int r = idx >> 4, c = idx & 15;
            As[c][r] = A[(long)(m0 + r) * lda + k0 + c];
        }
#pragma unroll
        for (int i = 0; i < 4; ++i) {
            int idx = tid + i * 256;
            int r = idx >> 6, c = idx & 63;
            Bs[r][c] = Bm[(long)(k0 + r) * ldb + n0 + c];
        }
        __syncthreads();
#pragma unroll
        for (int kk = 0; kk < GM_BK; ++kk) {
            float4 a4 = *(const float4*)&As[kk][ty * 4];
            float4 b4 = *(const float4*)&Bs[kk][tx * 4];
            float av[4] = {a4.x, a4.y, a4.z, a4.w};
            float bv[4] = {b4.x, b4.y, b4.z, b4.w};
#pragma unroll
            for (int i = 0; i < 4; ++i)
#pragma unroll
                for (int j = 0; j < 4; ++j)
                    acc[i][j] += av[i] * bv[j];
        }
        __syncthreads();
    }
#pragma unroll
    for (int i = 0; i < 4; ++i) {
        long m = m0 + ty * 4 + i;
#pragma unroll
        for (int j = 0; j < 4; ++j) {
            int n = n0 + tx * 4 + j;
            C[m * ldc + n] = acc[i][j];
        }
    }
}

// ---------------------------------------------------------------------------
// cb[k*768+o] = dot(fc_i_b, Wih[k][o][:]) + bih[k][o]
// ---------------------------------------------------------------------------
__global__ __launch_bounds__(256) void cb_kernel(
    const float* __restrict__ fc_i_b, const float* __restrict__ Wih,
    const float* __restrict__ bih, float* __restrict__ cb)
{
    long j = blockIdx.x;
    const float* row = Wih + j * 1024;
    float s = 0.f;
    for (int i = threadIdx.x; i < 1024; i += 256) s += fc_i_b[i] * row[i];
#pragma unroll
    for (int off = 32; off > 0; off >>= 1) s += __shfl_xor(s, off, 64);
    __shared__ float red[4];
    if ((threadIdx.x & 63) == 0) red[threadIdx.x >> 6] = s;
    __syncthreads();
    if (threadIdx.x == 0) cb[j] = red[0] + red[1] + red[2] + red[3] + bih[j];
}

// ---------------------------------------------------------------------------
// Per-b: s1[n] = dot(q[b,n,:], krow[b,:])/8 ; a = sigmoid(s1);
// mask[n]=0 for the 4 smallest s1 (index asc tie-break), else 1.
// One wave per b, 4 waves per block.
// ---------------------------------------------------------------------------
__global__ __launch_bounds__(256) void s1_mask_kernel(
    const float* __restrict__ qbuf,  // (B,8,64)
    const float* __restrict__ krow,  // (B,64)
    float* __restrict__ a_buf,       // (B,8)
    float* __restrict__ mask_buf)    // (B,8)
{
    const int wave = threadIdx.x >> 6;
    const int lane = threadIdx.x & 63;
    const long b = (long)blockIdx.x * 4 + wave;
    const float kr = krow[b * 64 + lane];
    float s1v[8];
#pragma unroll
    for (int n = 0; n < 8; ++n) {
        float p = qbuf[b * 512 + n * 64 + lane] * kr;
#pragma unroll
        for (int off = 32; off > 0; off >>= 1) p += __shfl_xor(p, off, 64);
        s1v[n] = p * 0.125f;
    }
    unsigned maskbits = 0;
#pragma unroll
    for (int n = 0; n < 8; ++n) {
        int rank = 0;
#pragma unroll
        for (int m = 0; m < 8; ++m) {
            if (m == n) continue;
            if (s1v[m] < s1v[n] || (s1v[m] == s1v[n] && m < n)) rank++;
        }
        if (rank >= 4) maskbits |= (1u << n);  // kept
    }
    if (lane < 8) {
        float sv = s1v[0];
#pragma unroll
        for (int n = 1; n < 8; ++n)
            if (lane == n) sv = s1v[n];
        a_buf[b * 8 + lane] = sigmoidf_(sv);
        mask_buf[b * 8 + lane] = ((maskbits >> lane) & 1u) ? 1.0f : 0.0f;
    }
}

// ---------------------------------------------------------------------------
// Fused big GEMM + GRU epilogue.
// accx[g] = dot(wfc[b,:1024], Wih[k][g*256+ol][:])   (scaled by a[b,k] + cb)
// acch[g] = dot(hx[b,k*256:+256], Whh[k][g*256+ol][:]) (+ bhh)
// r=sig(gx0+gh0); z=sig(gx1+gh1); n=tanh(gx2 + r*gh2); h=(1-z)n+z*hx
// Tile: 64 m-rows x 32 o_locals (x3 gates), 256 threads, thread = 4m x 2ol x 3g.
// ---------------------------------------------------------------------------
#define GR_BM 64
#define GR_BK 16

__global__ __launch_bounds__(256) void gru_fused(
    const float* __restrict__ wfc,   // (B,1024)
    const float* __restrict__ hx,    // (B,2048)
    const float* __restrict__ a_buf, // (B,8)
    const float* __restrict__ cb,    // (8,768)
    const float* __restrict__ Wih,   // (8,768,1024)
    const float* __restrict__ Whh,   // (8,768,256)
    const float* __restrict__ bhh,   // (8,768)
    float* __restrict__ hnew)        // (B,2048)
{
    const int kblk = blockIdx.z;
    const int m0 = blockIdx.y * GR_BM;
    const int ol0 = blockIdx.x * 32;
    const int tid = threadIdx.x;
    const int tx = tid & 15;   // ol-pair
    const int ty = tid >> 4;   // m-quad

    __shared__ float As[GR_BK][GR_BM + 4];
    __shared__ float Bs[96][GR_BK + 1];

    float accx[4][2][3] = {};
    float acch[4][2][3] = {};

    const float* Wihk = Wih + (long)kblk * 768 * 1024;
    const float* Whhk = Whh + (long)kblk * 768 * 256;

    // Phase 1: gx over K=1024
    for (int k0 = 0; k0 < 1024; k0 += GR_BK) {
#pragma unroll
        for (int i = 0; i < 4; ++i) {
            int idx = tid + i * 256;
            int r = idx >> 4, c = idx & 15;
            As[c][r] = wfc[(long)(m0 + r) * 1024 + k0 + c];
        }
#pragma unroll
        for (int i = 0; i < 6; ++i) {
            int idx = tid + i * 256;
            int r = idx >> 4, c = idx & 15;
            int ol_t = r / 3, g = r - ol_t * 3;
            Bs[r][c] = Wihk[(long)(g * 256 + ol0 + ol_t) * 1024 + k0 + c];
        }
        __syncthreads();
#pragma unroll
        for (int kk = 0; kk < GR_BK; ++kk) {
            float4 a4 = *(const float4*)&As[kk][ty * 4];
            float av[4] = {a4.x, a4.y, a4.z, a4.w};
#pragma unroll
            for (int jo = 0; jo < 2; ++jo) {
                int olt = tx * 2 + jo;
#pragma unroll
                for (int g = 0; g < 3; ++g) {
                    float bvv = Bs[olt * 3 + g][kk];
#pragma unroll
                    for (int im = 0; im < 4; ++im)
                        accx[im][jo][g] += av[im] * bvv;
                }
            }
        }
        __syncthreads();
    }

    // Phase 2: gh over K=256
    for (int k0 = 0; k0 < 256; k0 += GR_BK) {
#pragma unroll
        for (int i = 0; i < 4; ++i) {
            int idx = tid + i * 256;
            int r = idx >> 4, c = idx & 15;
            As[c][r] = hx[(long)(m0 + r) * 2048 + kblk * 256 + k0 + c];
        }
#pragma unroll
        for (int i = 0; i < 6; ++i) {
            int idx = tid + i * 256;
            int r = idx >> 4, c = idx & 15;
            int ol_t = r / 3, g = r - ol_t * 3;
            Bs[r][c] = Whhk[(long)(g * 256 + ol0 + ol_t) * 256 + k0 + c];
        }
        __syncthreads();
#pragma unroll
        for (int kk = 0; kk < GR_BK; ++kk) {
            float4 a4 = *(const float4*)&As[kk][ty * 4];
            float av[4] = {a4.x, a4.y, a4.z, a4.w};
#pragma unroll
            for (int jo = 0; jo < 2; ++jo) {
                int olt = tx * 2 + jo;
#pragma unroll
                for (int g = 0; g < 3; ++g) {
                    float bvv = Bs[olt * 3 + g][kk];
#pragma unroll
                    for (int im = 0; im < 4; ++im)
                        acch[im][jo][g] += av[im] * bvv;
                }
            }
        }
        __syncthreads();
    }

    // Epilogue: GRU
#pragma unroll
    for (int im = 0; im < 4; ++im) {
        long m = m0 + ty * 4 + im;
        float av = a_buf[m * 8 + kblk];
#pragma unroll
        for (int jo = 0; jo < 2; ++jo) {
            int ol = ol0 + tx * 2 + jo;
            float gx0 = av * accx[im][jo][0] + cb[kblk * 768 + ol];
            float gx1 = av * accx[im][jo][1] + cb[kblk * 768 + 256 + ol];
            float gx2 = av * accx[im][jo][2] + cb[kblk * 768 + 512 + ol];
            float gh0 = acch[im][jo][0] + bhh[kblk * 768 + ol];
            float gh1 = acch[im][jo][1] + bhh[kblk * 768 + 256 + ol];
            float gh2 = acch[im][jo][2] + bhh[kblk * 768 + 512 + ol];
            float r = sigmoidf_(gx0 + gh0);
            float z = sigmoidf_(gx1 + gh1);
            float nn = tanhf(gx2 + r * gh2);
            float hxv = hx[m * 2048 + kblk * 256 + ol];
            float h = (1.f - z) * nn + z * hxv;
            hnew[m * 2048 + kblk * 256 + ol] = h;
        }
    }
}

// ---------------------------------------------------------------------------
// Memory attention: per (b,h,qn): softmax over 8 kn of dot16/4, weighted vm sum.
// 32 threads per b, 8 b per block.
// ---------------------------------------------------------------------------
__global__ __launch_bounds__(256) void mattn_kernel(
    const float* __restrict__ qm, const float* __restrict__ km,
    const float* __restrict__ vm, float* __restrict__ omb)
{
    const int t = threadIdx.x;
    const int local = t & 31;
    const long b = (long)blockIdx.x * 8 + (t >> 5);
    const int h = local >> 3, qn = local & 7;
    const long base = b * 512 + h * 16;

    float qv[16];
#pragma unroll
    for (int i = 0; i < 4; ++i) {
        float4 v4 = *(const float4*)(qm + base + qn * 64 + i * 4);
        qv[i * 4 + 0] = v4.x; qv[i * 4 + 1] = v4.y; qv[i * 4 + 2] = v4.z; qv[i * 4 + 3] = v4.w;
    }
    float sc[8];
#pragma unroll
    for (int kn = 0; kn < 8; ++kn) {
        const float* kp = km + base + kn * 64;
        float s = 0.f;
#pragma unroll
        for (int i = 0; i < 4; ++i) {
            float4 v4 = *(const float4*)(kp + i * 4);
            s += qv[i * 4] * v4.x + qv[i * 4 + 1] * v4.y + qv[i * 4 + 2] * v4.z + qv[i * 4 + 3] * v4.w;
        }
        sc[kn] = s * 0.25f;
    }
    float mx = sc[0];
#pragma unroll
    for (int kn = 1; kn < 8; ++kn) mx = fmaxf(mx, sc[kn]);
    float ssum = 0.f;
#pragma unroll
    for (int kn = 0; kn < 8; ++kn) { sc[kn] = expf(sc[kn] - mx); ssum += sc[kn]; }
    float inv = 1.f / ssum;

    float acc[16] = {};
#pragma unroll
    for (int kn = 0; kn < 8; ++kn) {
        float w = sc[kn] * inv;
        const float* vp = vm + base + kn * 64;
#pragma unroll
        for (int i = 0; i < 4; ++i) {
            float4 v4 = *(const float4*)(vp + i * 4);
            acc[i * 4 + 0] += w * v4.x; acc[i * 4 + 1] += w * v4.y;
            acc[i * 4 + 2] += w * v4.z; acc[i * 4 + 3] += w * v4.w;
        }
    }
#pragma unroll
    for (int i = 0; i < 4; ++i) {
        float4 v4 = make_float4(acc[i * 4], acc[i * 4 + 1], acc[i * 4 + 2], acc[i * 4 + 3]);
        *(float4*)(omb + base + qn * 64 + i * 4) = v4;
    }
}

// ---------------------------------------------------------------------------
// Final: att = sig(om@gate_w+gb)*tanh(om@fc_w+fb); h2 = hnew + att;
// hx_out/cx_out = select(mask); mask_w = mask. hn_mask aliases hnew & mask_w
// region (read h first, then overwrite with mask) -> intentionally NOT restrict.
// Block: 4 b's, one n, o = tid.
// ---------------------------------------------------------------------------
__global__ __launch_bounds__(256) void final_kernel(
    const float* __restrict__ omb,
    float* hn_mask,
    const float* __restrict__ maskb,
    const float* __restrict__ hx, const float* __restrict__ cx,
    const float* __restrict__ fc_w, const float* __restrict__ fc_b,
    const float* __restrict__ gate_w, const float* __restrict__ gate_b,
    float* __restrict__ hx_out, float* __restrict__ cx_out)
{
    const int o = threadIdx.x;
    const int n = blockIdx.y;
    const long b0 = (long)blockIdx.x * 4;
    __shared__ float oml[4][64];
    {
        int j = threadIdx.x >> 6, d = threadIdx.x & 63;
        oml[j][d] = omb[(b0 + j) * 512 + n * 64 + d];
    }
    __syncthreads();
    float accf[4] = {}, accg[4] = {};
#pragma unroll 4
    for (int d = 0; d < 64; ++d) {
        float wf = fc_w[d * 256 + o];
        float wg = gate_w[d * 256 + o];
#pragma unroll
        for (int j = 0; j < 4; ++j) {
            accf[j] += oml[j][d] * wf;
            accg[j] += oml[j][d] * wg;
        }
    }
    const float fb = fc_b[o], gb = gate_b[o];
#pragma unroll
    for (int j = 0; j < 4; ++j) {
        long b = b0 + j;
        long idx = b * 2048 + (long)n * 256 + o;
        float att = sigmoidf_(accg[j] + gb) * tanhf(accf[j] + fb);
        float h2 = hn_mask[idx] + att;
        float mv = maskb[b * 8 + n];
        hx_out[idx] = (mv != 0.f) ? h2 : hx[idx];
        cx_out[idx] = (mv != 0.f) ? h2 : cx[idx];
        hn_mask[idx] = mv;
    }
}

// ---------------------------------------------------------------------------
extern "C" void kernel_launch(void* const* d_in, const int* in_sizes, int n_in,
                              void* d_out, int out_size, void* d_ws, size_t ws_size,
                              hipStream_t stream)
{
    const float* inp     = (const float*)d_in[0];
    const float* hx      = (const float*)d_in[1];
    const float* cx      = (const float*)d_in[2];
    // d_in[3] = step (unused)
    const float* Wq_i    = (const float*)d_in[4];
    const float* Wk_i    = (const float*)d_in[5];
    const float* Wv_i    = (const float*)d_in[6];
    const float* fc_i_w  = (const float*)d_in[7];
    const float* fc_i_b  = (const float*)d_in[8];
    const float* Wq_m    = (const float*)d_in[9];
    const float* Wk_m    = (const float*)d_in[10];
    const float* Wv_m    = (const float*)d_in[11];
    const float* fc_m_w  = (const float*)d_in[12];
    const float* fc_m_b  = (const float*)d_in[13];
    const float* gate_m_w= (const float*)d_in[14];
    const float* gate_m_b= (const float*)d_in[15];
    const float* Wih     = (const float*)d_in[16];
    const float* Whh     = (const float*)d_in[17];
    const float* bih     = (const float*)d_in[18];
    const float* bhh     = (const float*)d_in[19];

    float* out = (float*)d_out;
    const long BH = (long)B_SZ * NHID_;   // 8388608
    float* hx_out = out;
    float* cx_out = out + BH;
    float* mask_w = out + 2 * BH;
    float* hnew   = mask_w;               // staged here, overwritten by final_kernel

    float* w = (float*)d_ws;
    float* vrow  = w;                     // 4096*1024
    float* wfc   = w + 4194304;           // 4096*1024
    float* qbuf  = w + 8388608;           // 4096*512
    float* krow  = w + 10485760;          // 4096*64
    float* a_buf = w + 10747904;          // 4096*8
    float* maskb = w + 10780672;          // 4096*8
    float* cbuf  = w + 10813440;          // 6144
    // aliases (vrow/wfc/qbuf dead by the time these are written):
    float* qmb = w;                       // 4096*512
    float* kmb = w + 2097152;
    float* vmb = w + 4194304;
    float* omb = w + 6291456;

    // cb[k,o] = fc_i_b . Wih[k][o] + bih[k][o]
    cb_kernel<<<dim3(6144), dim3(256), 0, stream>>>(fc_i_b, Wih, bih, cbuf);
    // vrow = inp @ Wv_i[1]            (B,512)x(512,1024)
    gemm_nn<<<dim3(16, 64, 1), dim3(256), 0, stream>>>(
        inp, Wv_i + 512 * 1024, vrow, 4096, 1024, 512, 512, 1024, 1024, 0, 0, 0);
    // krow = inp @ Wk_i[1]            (B,512)x(512,64)
    gemm_nn<<<dim3(1, 64, 1), dim3(256), 0, stream>>>(
        inp, Wk_i + 512 * 64, krow, 4096, 64, 512, 512, 64, 64, 0, 0, 0);
    // q[b,n,:] = hx3[b,n] @ Wq_i[n]   batched z=8, (B,256)x(256,64)
    gemm_nn<<<dim3(1, 64, 8), dim3(256), 0, stream>>>(
        hx, Wq_i, qbuf, 4096, 64, 256, 2048, 64, 512, 256, 16384, 64);
    // s1 / a / mask
    s1_mask_kernel<<<dim3(1024), dim3(256), 0, stream>>>(qbuf, krow, a_buf, maskb);
    // wfc = vrow @ fc_i_w             (B,1024)x(1024,1024)
    gemm_nn<<<dim3(16, 64, 1), dim3(256), 0, stream>>>(
        vrow, fc_i_w, wfc, 4096, 1024, 1024, 1024, 1024, 1024, 0, 0, 0);
    // fused big GEMM + GRU -> hnew
    gru_fused<<<dim3(8, 64, 8), dim3(256), 0, stream>>>(
        wfc, hx, a_buf, cbuf, Wih, Whh, bhh, hnew);
    // qm/km/vm = hnew-blocks @ W*_m[n], batched z=8
    gemm_nn<<<dim3(1, 64, 8), dim3(256), 0, stream>>>(
        hnew, Wq_m, qmb, 4096, 64, 256, 2048, 64, 512, 256, 16384, 64);
    gemm_nn<<<dim3(1, 64, 8), dim3(256), 0, stream>>>(
        hnew, Wk_m, kmb, 4096, 64, 256, 2048, 64, 512, 256, 16384, 64);
    gemm_nn<<<dim3(1, 64, 8), dim3(256), 0, stream>>>(
        hnew, Wv_m, vmb, 4096, 64, 256, 2048, 64, 512, 256, 16384, 64);
    // memory attention -> om
    mattn_kernel<<<dim3(512), dim3(256), 0, stream>>>(qmb, kmb, vmb, omb);
    // fc/gate + final select
    final_kernel<<<dim3(1024, 8), dim3(256), 0, stream>>>(
        omb, hnew, maskb, hx, cx, fc_m_w, fc_m_b, gate_m_w, gate_m_b, hx_out, cx_out);
}

// Round 2
// 533.077 us; speedup vs baseline: 2.9937x; 2.9937x over previous
//
#include <hip/hip_runtime.h>
#include <hip/hip_bf16.h>

// Problem constants
#define B_SZ 4096
#define NHID_ 2048

typedef __bf16 bf16x8 __attribute__((ext_vector_type(8)));
typedef float f32x4 __attribute__((ext_vector_type(4)));

__device__ __forceinline__ float sigmoidf_(float x) { return 1.f / (1.f + expf(-x)); }

#define GLDS16(gp, lp) __builtin_amdgcn_global_load_lds( \
    (const __attribute__((address_space(1))) void*)(gp), \
    (__attribute__((address_space(3))) void*)(lp), 16, 0, 0)

// ---------------------------------------------------------------------------
// fp32 -> bf16 conversion, 4 elems/thread, grid-stride
// ---------------------------------------------------------------------------
__global__ __launch_bounds__(256) void f2b_kernel(
    const float* __restrict__ src, __hip_bfloat16* __restrict__ dst, long n4)
{
    long i = (long)blockIdx.x * 256 + threadIdx.x;
    const long stride = (long)gridDim.x * 256;
    for (; i < n4; i += stride) {
        float4 v = ((const float4*)src)[i];
        __hip_bfloat16 b0 = __float2bfloat16(v.x);
        __hip_bfloat16 b1 = __float2bfloat16(v.y);
        __hip_bfloat16 b2 = __float2bfloat16(v.z);
        __hip_bfloat16 b3 = __float2bfloat16(v.w);
        ushort4 u;
        u.x = *(unsigned short*)&b0; u.y = *(unsigned short*)&b1;
        u.z = *(unsigned short*)&b2; u.w = *(unsigned short*)&b3;
        ((ushort4*)dst)[i] = u;
    }
}

// ---------------------------------------------------------------------------
// Generic fp32 tiled GEMM (kept for the small helper GEMMs)
// ---------------------------------------------------------------------------
#define GM_BM 64
#define GM_BN 64
#define GM_BK 16

__global__ __launch_bounds__(256) void gemm_nn(
    const float* __restrict__ A, const float* __restrict__ Bm, float* __restrict__ C,
    int M, int N, int K, int lda, int ldb, int ldc,
    long sA, long sB, long sC)
{
    const int z = blockIdx.z;
    A += (long)z * sA; Bm += (long)z * sB; C += (long)z * sC;
    const int m0 = blockIdx.y * GM_BM;
    const int n0 = blockIdx.x * GM_BN;
    const int tid = threadIdx.x;
    const int tx = tid & 15;
    const int ty = tid >> 4;

    __shared__ float As[GM_BK][GM_BM + 4];
    __shared__ float Bs[GM_BK][GM_BN + 4];

    float acc[4][4] = {};

    for (int k0 = 0; k0 < K; k0 += GM_BK) {
#pragma unroll
        for (int i = 0; i < 4; ++i) {
            int idx = tid + i * 256;
            int r = idx >> 4, c = idx & 15;
            As[c][r] = A[(long)(m0 + r) * lda + k0 + c];
        }
#pragma unroll
        for (int i = 0; i < 4; ++i) {
            int idx = tid + i * 256;
            int r = idx >> 6, c = idx & 63;
            Bs[r][c] = Bm[(long)(k0 + r) * ldb + n0 + c];
        }
        __syncthreads();
#pragma unroll
        for (int kk = 0; kk < GM_BK; ++kk) {
            float4 a4 = *(const float4*)&As[kk][ty * 4];
            float4 b4 = *(const float4*)&Bs[kk][tx * 4];
            float av[4] = {a4.x, a4.y, a4.z, a4.w};
            float bv[4] = {b4.x, b4.y, b4.z, b4.w};
#pragma unroll
            for (int i = 0; i < 4; ++i)
#pragma unroll
                for (int j = 0; j < 4; ++j)
                    acc[i][j] += av[i] * bv[j];
        }
        __syncthreads();
    }
#pragma unroll
    for (int i = 0; i < 4; ++i) {
        long m = m0 + ty * 4 + i;
#pragma unroll
        for (int j = 0; j < 4; ++j) {
            int n = n0 + tx * 4 + j;
            C[m * ldc + n] = acc[i][j];
        }
    }
}

// Same GEMM but bf16 output (for wfc, consumed by the MFMA kernel)
__global__ __launch_bounds__(256) void gemm_nn_obf16(
    const float* __restrict__ A, const float* __restrict__ Bm, __hip_bfloat16* __restrict__ C,
    int M, int N, int K, int lda, int ldb, int ldc)
{
    const int m0 = blockIdx.y * GM_BM;
    const int n0 = blockIdx.x * GM_BN;
    const int tid = threadIdx.x;
    const int tx = tid & 15;
    const int ty = tid >> 4;

    __shared__ float As[GM_BK][GM_BM + 4];
    __shared__ float Bs[GM_BK][GM_BN + 4];

    float acc[4][4] = {};

    for (int k0 = 0; k0 < K; k0 += GM_BK) {
#pragma unroll
        for (int i = 0; i < 4; ++i) {
            int idx = tid + i * 256;
            int r = idx >> 4, c = idx & 15;
            As[c][r] = A[(long)(m0 + r) * lda + k0 + c];
        }
#pragma unroll
        for (int i = 0; i < 4; ++i) {
            int idx = tid + i * 256;
            int r = idx >> 6, c = idx & 63;
            Bs[r][c] = Bm[(long)(k0 + r) * ldb + n0 + c];
        }
        __syncthreads();
#pragma unroll
        for (int kk = 0; kk < GM_BK; ++kk) {
            float4 a4 = *(const float4*)&As[kk][ty * 4];
            float4 b4 = *(const float4*)&Bs[kk][tx * 4];
            float av[4] = {a4.x, a4.y, a4.z, a4.w};
            float bv[4] = {b4.x, b4.y, b4.z, b4.w};
#pragma unroll
            for (int i = 0; i < 4; ++i)
#pragma unroll
                for (int j = 0; j < 4; ++j)
                    acc[i][j] += av[i] * bv[j];
        }
        __syncthreads();
    }
#pragma unroll
    for (int i = 0; i < 4; ++i) {
        long m = m0 + ty * 4 + i;
#pragma unroll
        for (int j = 0; j < 4; ++j) {
            int n = n0 + tx * 4 + j;
            C[m * ldc + n] = __float2bfloat16(acc[i][j]);
        }
    }
}

// ---------------------------------------------------------------------------
// cb[k*768+o] = dot(fc_i_b, Wih[k][o][:]) + bih[k][o]
// ---------------------------------------------------------------------------
__global__ __launch_bounds__(256) void cb_kernel(
    const float* __restrict__ fc_i_b, const float* __restrict__ Wih,
    const float* __restrict__ bih, float* __restrict__ cb)
{
    long j = blockIdx.x;
    const float* row = Wih + j * 1024;
    float s = 0.f;
    for (int i = threadIdx.x; i < 1024; i += 256) s += fc_i_b[i] * row[i];
#pragma unroll
    for (int off = 32; off > 0; off >>= 1) s += __shfl_xor(s, off, 64);
    __shared__ float red[4];
    if ((threadIdx.x & 63) == 0) red[threadIdx.x >> 6] = s;
    __syncthreads();
    if (threadIdx.x == 0) cb[j] = red[0] + red[1] + red[2] + red[3] + bih[j];
}

// ---------------------------------------------------------------------------
// s1 / sigmoid(s1) / top-k mask
// ---------------------------------------------------------------------------
__global__ __launch_bounds__(256) void s1_mask_kernel(
    const float* __restrict__ qbuf,  // (B,8,64)
    const float* __restrict__ krow,  // (B,64)
    float* __restrict__ a_buf,       // (B,8)
    float* __restrict__ mask_buf)    // (B,8)
{
    const int wave = threadIdx.x >> 6;
    const int lane = threadIdx.x & 63;
    const long b = (long)blockIdx.x * 4 + wave;
    const float kr = krow[b * 64 + lane];
    float s1v[8];
#pragma unroll
    for (int n = 0; n < 8; ++n) {
        float p = qbuf[b * 512 + n * 64 + lane] * kr;
#pragma unroll
        for (int off = 32; off > 0; off >>= 1) p += __shfl_xor(p, off, 64);
        s1v[n] = p * 0.125f;
    }
    unsigned maskbits = 0;
#pragma unroll
    for (int n = 0; n < 8; ++n) {
        int rank = 0;
#pragma unroll
        for (int m = 0; m < 8; ++m) {
            if (m == n) continue;
            if (s1v[m] < s1v[n] || (s1v[m] == s1v[n] && m < n)) rank++;
        }
        if (rank >= 4) maskbits |= (1u << n);  // kept
    }
    if (lane < 8) {
        float sv = s1v[0];
#pragma unroll
        for (int n = 1; n < 8; ++n)
            if (lane == n) sv = s1v[n];
        a_buf[b * 8 + lane] = sigmoidf_(sv);
        mask_buf[b * 8 + lane] = ((maskbits >> lane) & 1u) ? 1.0f : 0.0f;
    }
}

// ---------------------------------------------------------------------------
// MFMA big GEMM + fused GRU epilogue.
// Block: 256 thr = 4 waves (2 row-waves x 2 ol-waves); tile 128 rows x 32 ols x 3 gates.
// LDS: A tile [128 rows][64 K] bf16 (16KB) + B tile [96 rows][64 K] (12KB),
// both XOR-swizzled (chunk ^= row&7) to kill the 128B-stride bank conflict;
// staged via global_load_lds w=16 with the inverse swizzle on the global source.
// ---------------------------------------------------------------------------
__global__ __launch_bounds__(256) void gru_fused_mfma(
    const __hip_bfloat16* __restrict__ wfcb,   // (B,1024) bf16
    const __hip_bfloat16* __restrict__ hxb,    // (B,2048) bf16
    const float* __restrict__ hx,              // (B,2048) fp32
    const float* __restrict__ a_buf,           // (B,8)
    const float* __restrict__ cb,              // (8,768)
    const __hip_bfloat16* __restrict__ Wihb,   // (8,768,1024) bf16
    const __hip_bfloat16* __restrict__ Whhb,   // (8,768,256) bf16
    const float* __restrict__ bhh,             // (8,768)
    float* __restrict__ hnew)                  // (B,2048)
{
    const int kblk = blockIdx.z;
    const int m0 = blockIdx.y * 128;
    const int ol0 = blockIdx.x * 32;
    const int tid = threadIdx.x;
    const int lane = tid & 63, wid = tid >> 6;
    const int wr = wid >> 1, wc = wid & 1;
    const int l15 = lane & 15, l4 = lane >> 4;

    __shared__ __align__(16) char lds_raw[16384 + 12288];
    char* Alds = lds_raw;
    char* Blds = lds_raw + 16384;

    f32x4 accx[4][3] = {};
    f32x4 acch[4][3] = {};

#define STAGE(Asrc, sA, Bsrc, sB, k0) do {                                     \
    _Pragma("unroll") for (int ii = 0; ii < 4; ++ii) {                         \
        int issue = ii * 4 + wid;                                              \
        int chunk = issue * 64 + lane;                                         \
        int r = chunk >> 3, cs = chunk & 7;                                    \
        int cl = cs ^ (r & 7);                                                 \
        const __hip_bfloat16* g = (Asrc) + (long)(m0 + r) * (sA) + (k0) + cl * 8; \
        GLDS16(g, Alds + issue * 1024);                                        \
    }                                                                          \
    _Pragma("unroll") for (int jj = 0; jj < 3; ++jj) {                         \
        int issue = jj * 4 + wid;                                              \
        int chunk = issue * 64 + lane;                                         \
        int r = chunk >> 3, cs = chunk & 7;                                    \
        int cl = cs ^ (r & 7);                                                 \
        int gg = r >> 5, oll = r & 31;                                         \
        const __hip_bfloat16* g = (Bsrc) + (long)(gg * 256 + ol0 + oll) * (sB) + (k0) + cl * 8; \
        GLDS16(g, Blds + issue * 1024);                                        \
    }                                                                          \
} while (0)

#define COMPUTE(acc) do {                                                      \
    _Pragma("unroll") for (int kk = 0; kk < 2; ++kk) {                         \
        bf16x8 af[4], bfr[3];                                                  \
        _Pragma("unroll") for (int im = 0; im < 4; ++im) {                     \
            int r = wr * 64 + im * 16 + l15;                                   \
            int cl = (kk * 4 + l4) ^ (l15 & 7);                                \
            af[im] = *(const bf16x8*)(Alds + r * 128 + cl * 16);               \
        }                                                                      \
        _Pragma("unroll") for (int g = 0; g < 3; ++g) {                        \
            int r = g * 32 + wc * 16 + l15;                                    \
            int cl = (kk * 4 + l4) ^ (l15 & 7);                                \
            bfr[g] = *(const bf16x8*)(Blds + r * 128 + cl * 16);               \
        }                                                                      \
        _Pragma("unroll") for (int im = 0; im < 4; ++im)                       \
            _Pragma("unroll") for (int g = 0; g < 3; ++g)                      \
                acc[im][g] = __builtin_amdgcn_mfma_f32_16x16x32_bf16(          \
                    af[im], bfr[g], acc[im][g], 0, 0, 0);                      \
    }                                                                          \
} while (0)

    // Phase 1: gx = wfc @ Wih[kblk]^T, K=1024
    const __hip_bfloat16* Wk = Wihb + (long)kblk * 768 * 1024;
    for (int k0 = 0; k0 < 1024; k0 += 64) {
        STAGE(wfcb, 1024, Wk, 1024, k0);
        __syncthreads();
        COMPUTE(accx);
        __syncthreads();
    }
    // Phase 2: gh = hx[:,kblk*256:+256] @ Whh[kblk]^T, K=256
    const __hip_bfloat16* Wh = Whhb + (long)kblk * 768 * 256;
    const __hip_bfloat16* hxk = hxb + kblk * 256;
    for (int k0 = 0; k0 < 256; k0 += 64) {
        STAGE(hxk, 2048, Wh, 256, k0);
        __syncthreads();
        COMPUTE(acch);
        __syncthreads();
    }
#undef STAGE
#undef COMPUTE

    // Epilogue: GRU nonlinearity (lane-local: accx/acch share C/D layout)
    const int ol = ol0 + wc * 16 + l15;
    const float* cbk = cb + kblk * 768;
    const float cb0 = cbk[ol], cb1 = cbk[256 + ol], cb2 = cbk[512 + ol];
    const float* bhk = bhh + kblk * 768;
    const float bh0 = bhk[ol], bh1 = bhk[256 + ol], bh2 = bhk[512 + ol];
#pragma unroll
    for (int im = 0; im < 4; ++im) {
#pragma unroll
        for (int reg = 0; reg < 4; ++reg) {
            long m = m0 + wr * 64 + im * 16 + l4 * 4 + reg;
            float av = a_buf[m * 8 + kblk];
            float gx0 = av * accx[im][0][reg] + cb0;
            float gx1 = av * accx[im][1][reg] + cb1;
            float gx2 = av * accx[im][2][reg] + cb2;
            float gh0 = acch[im][0][reg] + bh0;
            float gh1 = acch[im][1][reg] + bh1;
            float gh2 = acch[im][2][reg] + bh2;
            float rr = sigmoidf_(gx0 + gh0);
            float zz = sigmoidf_(gx1 + gh1);
            float nn = tanhf(gx2 + rr * gh2);
            long idx = m * 2048 + kblk * 256 + ol;
            float hxv = hx[idx];
            hnew[idx] = (1.f - zz) * nn + zz * hxv;
        }
    }
}

// ---------------------------------------------------------------------------
// Memory attention
// ---------------------------------------------------------------------------
__global__ __launch_bounds__(256) void mattn_kernel(
    const float* __restrict__ qm, const float* __restrict__ km,
    const float* __restrict__ vm, float* __restrict__ omb)
{
    const int t = threadIdx.x;
    const int local = t & 31;
    const long b = (long)blockIdx.x * 8 + (t >> 5);
    const int h = local >> 3, qn = local & 7;
    const long base = b * 512 + h * 16;

    float qv[16];
#pragma unroll
    for (int i = 0; i < 4; ++i) {
        float4 v4 = *(const float4*)(qm + base + qn * 64 + i * 4);
        qv[i * 4 + 0] = v4.x; qv[i * 4 + 1] = v4.y; qv[i * 4 + 2] = v4.z; qv[i * 4 + 3] = v4.w;
    }
    float sc[8];
#pragma unroll
    for (int kn = 0; kn < 8; ++kn) {
        const float* kp = km + base + kn * 64;
        float s = 0.f;
#pragma unroll
        for (int i = 0; i < 4; ++i) {
            float4 v4 = *(const float4*)(kp + i * 4);
            s += qv[i * 4] * v4.x + qv[i * 4 + 1] * v4.y + qv[i * 4 + 2] * v4.z + qv[i * 4 + 3] * v4.w;
        }
        sc[kn] = s * 0.25f;
    }
    float mx = sc[0];
#pragma unroll
    for (int kn = 1; kn < 8; ++kn) mx = fmaxf(mx, sc[kn]);
    float ssum = 0.f;
#pragma unroll
    for (int kn = 0; kn < 8; ++kn) { sc[kn] = expf(sc[kn] - mx); ssum += sc[kn]; }
    float inv = 1.f / ssum;

    float acc[16] = {};
#pragma unroll
    for (int kn = 0; kn < 8; ++kn) {
        float w = sc[kn] * inv;
        const float* vp = vm + base + kn * 64;
#pragma unroll
        for (int i = 0; i < 4; ++i) {
            float4 v4 = *(const float4*)(vp + i * 4);
            acc[i * 4 + 0] += w * v4.x; acc[i * 4 + 1] += w * v4.y;
            acc[i * 4 + 2] += w * v4.z; acc[i * 4 + 3] += w * v4.w;
        }
    }
#pragma unroll
    for (int i = 0; i < 4; ++i) {
        float4 v4 = make_float4(acc[i * 4], acc[i * 4 + 1], acc[i * 4 + 2], acc[i * 4 + 3]);
        *(float4*)(omb + base + qn * 64 + i * 4) = v4;
    }
}

// ---------------------------------------------------------------------------
// Final: att + masked select. hn_mask aliases hnew & mask_w region.
// ---------------------------------------------------------------------------
__global__ __launch_bounds__(256) void final_kernel(
    const float* __restrict__ omb,
    float* hn_mask,
    const float* __restrict__ maskb,
    const float* __restrict__ hx, const float* __restrict__ cx,
    const float* __restrict__ fc_w, const float* __restrict__ fc_b,
    const float* __restrict__ gate_w, const float* __restrict__ gate_b,
    float* __restrict__ hx_out, float* __restrict__ cx_out)
{
    const int o = threadIdx.x;
    const int n = blockIdx.y;
    const long b0 = (long)blockIdx.x * 4;
    __shared__ float oml[4][64];
    {
        int j = threadIdx.x >> 6, d = threadIdx.x & 63;
        oml[j][d] = omb[(b0 + j) * 512 + n * 64 + d];
    }
    __syncthreads();
    float accf[4] = {}, accg[4] = {};
#pragma unroll 4
    for (int d = 0; d < 64; ++d) {
        float wf = fc_w[d * 256 + o];
        float wg = gate_w[d * 256 + o];
#pragma unroll
        for (int j = 0; j < 4; ++j) {
            accf[j] += oml[j][d] * wf;
            accg[j] += oml[j][d] * wg;
        }
    }
    const float fb = fc_b[o], gb = gate_b[o];
#pragma unroll
    for (int j = 0; j < 4; ++j) {
        long b = b0 + j;
        long idx = b * 2048 + (long)n * 256 + o;
        float att = sigmoidf_(accg[j] + gb) * tanhf(accf[j] + fb);
        float h2 = hn_mask[idx] + att;
        float mv = maskb[b * 8 + n];
        hx_out[idx] = (mv != 0.f) ? h2 : hx[idx];
        cx_out[idx] = (mv != 0.f) ? h2 : cx[idx];
        hn_mask[idx] = mv;
    }
}

// ---------------------------------------------------------------------------
extern "C" void kernel_launch(void* const* d_in, const int* in_sizes, int n_in,
                              void* d_out, int out_size, void* d_ws, size_t ws_size,
                              hipStream_t stream)
{
    const float* inp     = (const float*)d_in[0];
    const float* hx      = (const float*)d_in[1];
    const float* cx      = (const float*)d_in[2];
    const float* Wq_i    = (const float*)d_in[4];
    const float* Wk_i    = (const float*)d_in[5];
    const float* Wv_i    = (const float*)d_in[6];
    const float* fc_i_w  = (const float*)d_in[7];
    const float* fc_i_b  = (const float*)d_in[8];
    const float* Wq_m    = (const float*)d_in[9];
    const float* Wk_m    = (const float*)d_in[10];
    const float* Wv_m    = (const float*)d_in[11];
    const float* fc_m_w  = (const float*)d_in[12];
    const float* fc_m_b  = (const float*)d_in[13];
    const float* gate_m_w= (const float*)d_in[14];
    const float* gate_m_b= (const float*)d_in[15];
    const float* Wih     = (const float*)d_in[16];
    const float* Whh     = (const float*)d_in[17];
    const float* bih     = (const float*)d_in[18];
    const float* bhh     = (const float*)d_in[19];

    float* out = (float*)d_out;
    const long BH = (long)B_SZ * NHID_;   // 8388608
    float* hx_out = out;
    float* cx_out = out + BH;
    float* mask_w = out + 2 * BH;
    float* hnew   = mask_w;                     // staged here, overwritten by final_kernel
    __hip_bfloat16* hxb = (__hip_bfloat16*)out; // hx bf16 staged in hx_out region (dead until final)

    float* w = (float*)d_ws;
    float* vrow  = w;                                   // [0, 4194304)
    __hip_bfloat16* wfcb = (__hip_bfloat16*)(w + 4194304); // 4096x1024 bf16 (2097152 f)
    float* qbuf  = w + 6291456;                         // 4096*512
    float* krow  = w + 8388608;                         // 4096*64
    float* a_buf = w + 8650752;                         // 4096*8
    float* maskb = w + 8683520;                         // 4096*8
    float* cbuf  = w + 8716288;                         // 6144
    // bf16 weights overlay vrow (dead after wfc gemm):
    __hip_bfloat16* Wihb = (__hip_bfloat16*)(w);            // 6291456 bf16 = 3145728 f
    __hip_bfloat16* Whhb = (__hip_bfloat16*)(w + 3145728);  // 1572864 bf16 = 786432 f
    // post-gru aliases (vrow/wfcb/qbuf all dead):
    float* qmb = w;                       // 4096*512
    float* kmb = w + 2097152;
    float* vmb = w + 4194304;
    float* omb = w + 6291456;

    // cb[k,o] = fc_i_b . Wih[k][o] + bih[k][o]
    cb_kernel<<<dim3(6144), dim3(256), 0, stream>>>(fc_i_b, Wih, bih, cbuf);
    // hx -> bf16 (into hx_out region of d_out)
    f2b_kernel<<<dim3(2048), dim3(256), 0, stream>>>(hx, hxb, 2097152);
    // vrow = inp @ Wv_i[1]            (B,512)x(512,1024)
    gemm_nn<<<dim3(16, 64, 1), dim3(256), 0, stream>>>(
        inp, Wv_i + 512 * 1024, vrow, 4096, 1024, 512, 512, 1024, 1024, 0, 0, 0);
    // krow = inp @ Wk_i[1]            (B,512)x(512,64)
    gemm_nn<<<dim3(1, 64, 1), dim3(256), 0, stream>>>(
        inp, Wk_i + 512 * 64, krow, 4096, 64, 512, 512, 64, 64, 0, 0, 0);
    // q[b,n,:] = hx3[b,n] @ Wq_i[n]   batched z=8
    gemm_nn<<<dim3(1, 64, 8), dim3(256), 0, stream>>>(
        hx, Wq_i, qbuf, 4096, 64, 256, 2048, 64, 512, 256, 16384, 64);
    // s1 / a / mask
    s1_mask_kernel<<<dim3(1024), dim3(256), 0, stream>>>(qbuf, krow, a_buf, maskb);
    // wfc = vrow @ fc_i_w -> bf16     (B,1024)x(1024,1024)
    gemm_nn_obf16<<<dim3(16, 64, 1), dim3(256), 0, stream>>>(
        vrow, fc_i_w, wfcb, 4096, 1024, 1024, 1024, 1024, 1024);
    // weight conversions (overlay vrow, now dead)
    f2b_kernel<<<dim3(2048), dim3(256), 0, stream>>>(Wih, Wihb, 1572864);
    f2b_kernel<<<dim3(1024), dim3(256), 0, stream>>>(Whh, Whhb, 393216);
    // fused MFMA GEMM + GRU -> hnew
    gru_fused_mfma<<<dim3(8, 32, 8), dim3(256), 0, stream>>>(
        wfcb, hxb, hx, a_buf, cbuf, Wihb, Whhb, bhh, hnew);
    // qm/km/vm = hnew-blocks @ W*_m[n], batched z=8
    gemm_nn<<<dim3(1, 64, 8), dim3(256), 0, stream>>>(
        hnew, Wq_m, qmb, 4096, 64, 256, 2048, 64, 512, 256, 16384, 64);
    gemm_nn<<<dim3(1, 64, 8), dim3(256), 0, stream>>>(
        hnew, Wk_m, kmb, 4096, 64, 256, 2048, 64, 512, 256, 16384, 64);
    gemm_nn<<<dim3(1, 64, 8), dim3(256), 0, stream>>>(
        hnew, Wv_m, vmb, 4096, 64, 256, 2048, 64, 512, 256, 16384, 64);
    // memory attention -> om
    mattn_kernel<<<dim3(512), dim3(256), 0, stream>>>(qmb, kmb, vmb, omb);
    // fc/gate + final select
    final_kernel<<<dim3(1024, 8), dim3(256), 0, stream>>>(
        omb, hnew, maskb, hx, cx, fc_m_w, fc_m_b, gate_m_w, gate_m_b, hx_out, cx_out);
}

// Round 3
// 328.371 us; speedup vs baseline: 4.8599x; 1.6234x over previous
//
#include <hip/hip_runtime.h>
#include <hip/hip_bf16.h>

// Problem constants
#define B_SZ 4096
#define NHID_ 2048

typedef __bf16 bf16x8 __attribute__((ext_vector_type(8)));
typedef float f32x4 __attribute__((ext_vector_type(4)));

__device__ __forceinline__ float sigmoidf_(float x) { return 1.f / (1.f + expf(-x)); }

#define GLDS16(gp, lp) __builtin_amdgcn_global_load_lds( \
    (const __attribute__((address_space(1))) void*)(gp), \
    (__attribute__((address_space(3))) void*)(lp), 16, 0, 0)

// ---------------------------------------------------------------------------
// fp32 -> bf16 conversion, 4 elems/thread, grid-stride
// ---------------------------------------------------------------------------
__global__ __launch_bounds__(256) void f2b_kernel(
    const float* __restrict__ src, __hip_bfloat16* __restrict__ dst, long n4)
{
    long i = (long)blockIdx.x * 256 + threadIdx.x;
    const long stride = (long)gridDim.x * 256;
    for (; i < n4; i += stride) {
        float4 v = ((const float4*)src)[i];
        __hip_bfloat16 b0 = __float2bfloat16(v.x);
        __hip_bfloat16 b1 = __float2bfloat16(v.y);
        __hip_bfloat16 b2 = __float2bfloat16(v.z);
        __hip_bfloat16 b3 = __float2bfloat16(v.w);
        ushort4 u;
        u.x = *(unsigned short*)&b0; u.y = *(unsigned short*)&b1;
        u.z = *(unsigned short*)&b2; u.w = *(unsigned short*)&b3;
        ((ushort4*)dst)[i] = u;
    }
}

// ---------------------------------------------------------------------------
// Transpose + convert: dst[c*ldd + r] (bf16) = src[r*C + c] (f32), batched z.
// 32x32 tiles, coalesced both sides.
// ---------------------------------------------------------------------------
__global__ __launch_bounds__(256) void tconv_kernel(
    const float* __restrict__ src, int C, long sS,
    __hip_bfloat16* __restrict__ dst, int ldd, long sD)
{
    src += (long)blockIdx.z * sS;
    dst += (long)blockIdx.z * sD;
    const int r0 = blockIdx.y * 32, c0 = blockIdx.x * 32;
    const int tx = threadIdx.x & 31, ty = threadIdx.x >> 5;
    __shared__ float tile[32][33];
#pragma unroll
    for (int i = 0; i < 4; ++i)
        tile[ty + i * 8][tx] = src[(long)(r0 + ty + i * 8) * C + c0 + tx];
    __syncthreads();
#pragma unroll
    for (int i = 0; i < 4; ++i)
        dst[(long)(c0 + ty + i * 8) * ldd + r0 + tx] = __float2bfloat16(tile[tx][ty + i * 8]);
}

// ---------------------------------------------------------------------------
// Generic fp32 tiled GEMM (kept for the mask-precision-critical helpers)
// ---------------------------------------------------------------------------
#define GM_BM 64
#define GM_BN 64
#define GM_BK 16

__global__ __launch_bounds__(256) void gemm_nn(
    const float* __restrict__ A, const float* __restrict__ Bm, float* __restrict__ C,
    int M, int N, int K, int lda, int ldb, int ldc,
    long sA, long sB, long sC)
{
    const int z = blockIdx.z;
    A += (long)z * sA; Bm += (long)z * sB; C += (long)z * sC;
    const int m0 = blockIdx.y * GM_BM;
    const int n0 = blockIdx.x * GM_BN;
    const int tid = threadIdx.x;
    const int tx = tid & 15;
    const int ty = tid >> 4;

    __shared__ float As[GM_BK][GM_BM + 4];
    __shared__ float Bs[GM_BK][GM_BN + 4];

    float acc[4][4] = {};

    for (int k0 = 0; k0 < K; k0 += GM_BK) {
#pragma unroll
        for (int i = 0; i < 4; ++i) {
            int idx = tid + i * 256;
            int r = idx >> 4, c = idx & 15;
            As[c][r] = A[(long)(m0 + r) * lda + k0 + c];
        }
#pragma unroll
        for (int i = 0; i < 4; ++i) {
            int idx = tid + i * 256;
            int r = idx >> 6, c = idx & 63;
            Bs[r][c] = Bm[(long)(k0 + r) * ldb + n0 + c];
        }
        __syncthreads();
#pragma unroll
        for (int kk = 0; kk < GM_BK; ++kk) {
            float4 a4 = *(const float4*)&As[kk][ty * 4];
            float4 b4 = *(const float4*)&Bs[kk][tx * 4];
            float av[4] = {a4.x, a4.y, a4.z, a4.w};
            float bv[4] = {b4.x, b4.y, b4.z, b4.w};
#pragma unroll
            for (int i = 0; i < 4; ++i)
#pragma unroll
                for (int j = 0; j < 4; ++j)
                    acc[i][j] += av[i] * bv[j];
        }
        __syncthreads();
    }
#pragma unroll
    for (int i = 0; i < 4; ++i) {
        long m = m0 + ty * 4 + i;
#pragma unroll
        for (int j = 0; j < 4; ++j) {
            int n = n0 + tx * 4 + j;
            C[m * ldc + n] = acc[i][j];
        }
    }
}

// ---------------------------------------------------------------------------
// MFMA GEMM: C(bf16, M x N) = A(bf16, M x K, lda) @ BT(bf16, N x K, ldb)^T
// Block: 4 waves (2x2), tile 128M x 64N, K-step 64.
// LDS XOR-swizzled (both-sides, via pre-swizzled global source).
// ---------------------------------------------------------------------------
__global__ __launch_bounds__(256) void gemm_mfma_obf16(
    const __hip_bfloat16* __restrict__ A, int lda,
    const __hip_bfloat16* __restrict__ BT, int ldb,
    __hip_bfloat16* __restrict__ C, int ldc, int K)
{
    const int m0 = blockIdx.y * 128;
    const int n0 = blockIdx.x * 64;
    const int tid = threadIdx.x;
    const int lane = tid & 63, wid = tid >> 6;
    const int wr = wid >> 1, wc = wid & 1;
    const int l15 = lane & 15, l4 = lane >> 4;

    __shared__ __align__(16) char lds_raw[16384 + 8192];
    char* Alds = lds_raw;
    char* Blds = lds_raw + 16384;

    f32x4 acc[4][2] = {};

    for (int k0 = 0; k0 < K; k0 += 64) {
#pragma unroll
        for (int ii = 0; ii < 4; ++ii) {
            int issue = ii * 4 + wid;
            int chunk = issue * 64 + lane;
            int r = chunk >> 3, cs = chunk & 7;
            int cl = cs ^ (r & 7);
            const __hip_bfloat16* g = A + (long)(m0 + r) * lda + k0 + cl * 8;
            GLDS16(g, Alds + issue * 1024);
        }
#pragma unroll
        for (int jj = 0; jj < 2; ++jj) {
            int issue = jj * 4 + wid;
            int chunk = issue * 64 + lane;
            int r = chunk >> 3, cs = chunk & 7;
            int cl = cs ^ (r & 7);
            const __hip_bfloat16* g = BT + (long)(n0 + r) * ldb + k0 + cl * 8;
            GLDS16(g, Blds + issue * 1024);
        }
        __syncthreads();
#pragma unroll
        for (int kk = 0; kk < 2; ++kk) {
            bf16x8 af[4], bfr[2];
#pragma unroll
            for (int im = 0; im < 4; ++im) {
                int r = wr * 64 + im * 16 + l15;
                int cl = (kk * 4 + l4) ^ (l15 & 7);
                af[im] = *(const bf16x8*)(Alds + r * 128 + cl * 16);
            }
#pragma unroll
            for (int jn = 0; jn < 2; ++jn) {
                int r = wc * 32 + jn * 16 + l15;
                int cl = (kk * 4 + l4) ^ (l15 & 7);
                bfr[jn] = *(const bf16x8*)(Blds + r * 128 + cl * 16);
            }
#pragma unroll
            for (int im = 0; im < 4; ++im)
#pragma unroll
                for (int jn = 0; jn < 2; ++jn)
                    acc[im][jn] = __builtin_amdgcn_mfma_f32_16x16x32_bf16(
                        af[im], bfr[jn], acc[im][jn], 0, 0, 0);
        }
        __syncthreads();
    }
#pragma unroll
    for (int im = 0; im < 4; ++im)
#pragma unroll
        for (int reg = 0; reg < 4; ++reg) {
            long m = m0 + wr * 64 + im * 16 + l4 * 4 + reg;
#pragma unroll
            for (int jn = 0; jn < 2; ++jn) {
                int n = n0 + wc * 32 + jn * 16 + l15;
                C[m * ldc + n] = __float2bfloat16(acc[im][jn][reg]);
            }
        }
}

// ---------------------------------------------------------------------------
// Fused q/k/v_m projections: per z=n-block,
// C[b, 0:192] = hnewb[b, z*256:+256] @ WmT[z]^T ; cols 0:64->qmb, 64:128->kmb,
// 128:192->vmb, each written as (B,8,64) at qout + g*2097152.
// ---------------------------------------------------------------------------
__global__ __launch_bounds__(256) void gemm_mfma_qkv(
    const __hip_bfloat16* __restrict__ hnewb,  // (B,2048)
    const __hip_bfloat16* __restrict__ WmT,    // (8,192,256)
    float* __restrict__ qout)                  // qmb | kmb | vmb (each 2097152 f)
{
    const int z = blockIdx.z;
    const int m0 = blockIdx.y * 128;
    const int n0 = blockIdx.x * 64;
    const int tid = threadIdx.x;
    const int lane = tid & 63, wid = tid >> 6;
    const int wr = wid >> 1, wc = wid & 1;
    const int l15 = lane & 15, l4 = lane >> 4;

    const __hip_bfloat16* A = hnewb + z * 256;
    const __hip_bfloat16* BT = WmT + (long)z * 192 * 256;

    __shared__ __align__(16) char lds_raw[16384 + 8192];
    char* Alds = lds_raw;
    char* Blds = lds_raw + 16384;

    f32x4 acc[4][2] = {};

    for (int k0 = 0; k0 < 256; k0 += 64) {
#pragma unroll
        for (int ii = 0; ii < 4; ++ii) {
            int issue = ii * 4 + wid;
            int chunk = issue * 64 + lane;
            int r = chunk >> 3, cs = chunk & 7;
            int cl = cs ^ (r & 7);
            const __hip_bfloat16* g = A + (long)(m0 + r) * 2048 + k0 + cl * 8;
            GLDS16(g, Alds + issue * 1024);
        }
#pragma unroll
        for (int jj = 0; jj < 2; ++jj) {
            int issue = jj * 4 + wid;
            int chunk = issue * 64 + lane;
            int r = chunk >> 3, cs = chunk & 7;
            int cl = cs ^ (r & 7);
            const __hip_bfloat16* g = BT + (long)(n0 + r) * 256 + k0 + cl * 8;
            GLDS16(g, Blds + issue * 1024);
        }
        __syncthreads();
#pragma unroll
        for (int kk = 0; kk < 2; ++kk) {
            bf16x8 af[4], bfr[2];
#pragma unroll
            for (int im = 0; im < 4; ++im) {
                int r = wr * 64 + im * 16 + l15;
                int cl = (kk * 4 + l4) ^ (l15 & 7);
                af[im] = *(const bf16x8*)(Alds + r * 128 + cl * 16);
            }
#pragma unroll
            for (int jn = 0; jn < 2; ++jn) {
                int r = wc * 32 + jn * 16 + l15;
                int cl = (kk * 4 + l4) ^ (l15 & 7);
                bfr[jn] = *(const bf16x8*)(Blds + r * 128 + cl * 16);
            }
#pragma unroll
            for (int im = 0; im < 4; ++im)
#pragma unroll
                for (int jn = 0; jn < 2; ++jn)
                    acc[im][jn] = __builtin_amdgcn_mfma_f32_16x16x32_bf16(
                        af[im], bfr[jn], acc[im][jn], 0, 0, 0);
        }
        __syncthreads();
    }
#pragma unroll
    for (int jn = 0; jn < 2; ++jn) {
        int j = n0 + wc * 32 + jn * 16 + l15;   // [0,192)
        int g = j >> 6, d = j & 63;
        float* outp = qout + (long)g * 2097152 + (long)z * 64 + d;
#pragma unroll
        for (int im = 0; im < 4; ++im)
#pragma unroll
            for (int reg = 0; reg < 4; ++reg) {
                long m = m0 + wr * 64 + im * 16 + l4 * 4 + reg;
                outp[m * 512] = acc[im][jn][reg];
            }
    }
}

// ---------------------------------------------------------------------------
// cb[k*768+o] = dot(fc_i_b, Wih[k][o][:]) + bih[k][o]
// ---------------------------------------------------------------------------
__global__ __launch_bounds__(256) void cb_kernel(
    const float* __restrict__ fc_i_b, const float* __restrict__ Wih,
    const float* __restrict__ bih, float* __restrict__ cb)
{
    long j = blockIdx.x;
    const float* row = Wih + j * 1024;
    float s = 0.f;
    for (int i = threadIdx.x; i < 1024; i += 256) s += fc_i_b[i] * row[i];
#pragma unroll
    for (int off = 32; off > 0; off >>= 1) s += __shfl_xor(s, off, 64);
    __shared__ float red[4];
    if ((threadIdx.x & 63) == 0) red[threadIdx.x >> 6] = s;
    __syncthreads();
    if (threadIdx.x == 0) cb[j] = red[0] + red[1] + red[2] + red[3] + bih[j];
}

// ---------------------------------------------------------------------------
// s1 / sigmoid(s1) / top-k mask (fp32 — mask decisions are precision-critical)
// ---------------------------------------------------------------------------
__global__ __launch_bounds__(256) void s1_mask_kernel(
    const float* __restrict__ qbuf,  // (B,8,64)
    const float* __restrict__ krow,  // (B,64)
    float* __restrict__ a_buf,       // (B,8)
    float* __restrict__ mask_buf)    // (B,8)
{
    const int wave = threadIdx.x >> 6;
    const int lane = threadIdx.x & 63;
    const long b = (long)blockIdx.x * 4 + wave;
    const float kr = krow[b * 64 + lane];
    float s1v[8];
#pragma unroll
    for (int n = 0; n < 8; ++n) {
        float p = qbuf[b * 512 + n * 64 + lane] * kr;
#pragma unroll
        for (int off = 32; off > 0; off >>= 1) p += __shfl_xor(p, off, 64);
        s1v[n] = p * 0.125f;
    }
    unsigned maskbits = 0;
#pragma unroll
    for (int n = 0; n < 8; ++n) {
        int rank = 0;
#pragma unroll
        for (int m = 0; m < 8; ++m) {
            if (m == n) continue;
            if (s1v[m] < s1v[n] || (s1v[m] == s1v[n] && m < n)) rank++;
        }
        if (rank >= 4) maskbits |= (1u << n);  // kept
    }
    if (lane < 8) {
        float sv = s1v[0];
#pragma unroll
        for (int n = 1; n < 8; ++n)
            if (lane == n) sv = s1v[n];
        a_buf[b * 8 + lane] = sigmoidf_(sv);
        mask_buf[b * 8 + lane] = ((maskbits >> lane) & 1u) ? 1.0f : 0.0f;
    }
}

// ---------------------------------------------------------------------------
// MFMA big GEMM + fused GRU epilogue (now also emits hnewb bf16).
// ---------------------------------------------------------------------------
__global__ __launch_bounds__(256) void gru_fused_mfma(
    const __hip_bfloat16* __restrict__ wfcb,   // (B,1024) bf16
    const __hip_bfloat16* __restrict__ hxb,    // (B,2048) bf16
    const float* __restrict__ hx,              // (B,2048) fp32
    const float* __restrict__ a_buf,           // (B,8)
    const float* __restrict__ cb,              // (8,768)
    const __hip_bfloat16* __restrict__ Wihb,   // (8,768,1024) bf16
    const __hip_bfloat16* __restrict__ Whhb,   // (8,768,256) bf16
    const float* __restrict__ bhh,             // (8,768)
    float* __restrict__ hnew,                  // (B,2048) f32
    __hip_bfloat16* __restrict__ hnewb)        // (B,2048) bf16
{
    const int kblk = blockIdx.z;
    const int m0 = blockIdx.y * 128;
    const int ol0 = blockIdx.x * 32;
    const int tid = threadIdx.x;
    const int lane = tid & 63, wid = tid >> 6;
    const int wr = wid >> 1, wc = wid & 1;
    const int l15 = lane & 15, l4 = lane >> 4;

    __shared__ __align__(16) char lds_raw[16384 + 12288];
    char* Alds = lds_raw;
    char* Blds = lds_raw + 16384;

    f32x4 accx[4][3] = {};
    f32x4 acch[4][3] = {};

#define STAGE(Asrc, sA, Bsrc, sB, k0) do {                                     \
    _Pragma("unroll") for (int ii = 0; ii < 4; ++ii) {                         \
        int issue = ii * 4 + wid;                                              \
        int chunk = issue * 64 + lane;                                         \
        int r = chunk >> 3, cs = chunk & 7;                                    \
        int cl = cs ^ (r & 7);                                                 \
        const __hip_bfloat16* g = (Asrc) + (long)(m0 + r) * (sA) + (k0) + cl * 8; \
        GLDS16(g, Alds + issue * 1024);                                        \
    }                                                                          \
    _Pragma("unroll") for (int jj = 0; jj < 3; ++jj) {                         \
        int issue = jj * 4 + wid;                                              \
        int chunk = issue * 64 + lane;                                         \
        int r = chunk >> 3, cs = chunk & 7;                                    \
        int cl = cs ^ (r & 7);                                                 \
        int gg = r >> 5, oll = r & 31;                                         \
        const __hip_bfloat16* g = (Bsrc) + (long)(gg * 256 + ol0 + oll) * (sB) + (k0) + cl * 8; \
        GLDS16(g, Blds + issue * 1024);                                        \
    }                                                                          \
} while (0)

#define COMPUTE(acc) do {                                                      \
    _Pragma("unroll") for (int kk = 0; kk < 2; ++kk) {                         \
        bf16x8 af[4], bfr[3];                                                  \
        _Pragma("unroll") for (int im = 0; im < 4; ++im) {                     \
            int r = wr * 64 + im * 16 + l15;                                   \
            int cl = (kk * 4 + l4) ^ (l15 & 7);                                \
            af[im] = *(const bf16x8*)(Alds + r * 128 + cl * 16);               \
        }                                                                      \
        _Pragma("unroll") for (int g = 0; g < 3; ++g) {                        \
            int r = g * 32 + wc * 16 + l15;                                    \
            int cl = (kk * 4 + l4) ^ (l15 & 7);                                \
            bfr[g] = *(const bf16x8*)(Blds + r * 128 + cl * 16);               \
        }                                                                      \
        _Pragma("unroll") for (int im = 0; im < 4; ++im)                       \
            _Pragma("unroll") for (int g = 0; g < 3; ++g)                      \
                acc[im][g] = __builtin_amdgcn_mfma_f32_16x16x32_bf16(          \
                    af[im], bfr[g], acc[im][g], 0, 0, 0);                      \
    }                                                                          \
} while (0)

    // Phase 1: gx = wfc @ Wih[kblk]^T, K=1024
    const __hip_bfloat16* Wk = Wihb + (long)kblk * 768 * 1024;
    for (int k0 = 0; k0 < 1024; k0 += 64) {
        STAGE(wfcb, 1024, Wk, 1024, k0);
        __syncthreads();
        COMPUTE(accx);
        __syncthreads();
    }
    // Phase 2: gh = hx[:,kblk*256:+256] @ Whh[kblk]^T, K=256
    const __hip_bfloat16* Wh = Whhb + (long)kblk * 768 * 256;
    const __hip_bfloat16* hxk = hxb + kblk * 256;
    for (int k0 = 0; k0 < 256; k0 += 64) {
        STAGE(hxk, 2048, Wh, 256, k0);
        __syncthreads();
        COMPUTE(acch);
        __syncthreads();
    }
#undef STAGE
#undef COMPUTE

    // Epilogue: GRU nonlinearity (lane-local: accx/acch share C/D layout)
    const int ol = ol0 + wc * 16 + l15;
    const float* cbk = cb + kblk * 768;
    const float cb0 = cbk[ol], cb1 = cbk[256 + ol], cb2 = cbk[512 + ol];
    const float* bhk = bhh + kblk * 768;
    const float bh0 = bhk[ol], bh1 = bhk[256 + ol], bh2 = bhk[512 + ol];
#pragma unroll
    for (int im = 0; im < 4; ++im) {
#pragma unroll
        for (int reg = 0; reg < 4; ++reg) {
            long m = m0 + wr * 64 + im * 16 + l4 * 4 + reg;
            float av = a_buf[m * 8 + kblk];
            float gx0 = av * accx[im][0][reg] + cb0;
            float gx1 = av * accx[im][1][reg] + cb1;
            float gx2 = av * accx[im][2][reg] + cb2;
            float gh0 = acch[im][0][reg] + bh0;
            float gh1 = acch[im][1][reg] + bh1;
            float gh2 = acch[im][2][reg] + bh2;
            float rr = sigmoidf_(gx0 + gh0);
            float zz = sigmoidf_(gx1 + gh1);
            float nn = tanhf(gx2 + rr * gh2);
            long idx = m * 2048 + kblk * 256 + ol;
            float hxv = hx[idx];
            float h = (1.f - zz) * nn + zz * hxv;
            hnew[idx] = h;
            hnewb[idx] = __float2bfloat16(h);
        }
    }
}

// ---------------------------------------------------------------------------
// Memory attention
// ---------------------------------------------------------------------------
__global__ __launch_bounds__(256) void mattn_kernel(
    const float* __restrict__ qm, const float* __restrict__ km,
    const float* __restrict__ vm, float* __restrict__ omb)
{
    const int t = threadIdx.x;
    const int local = t & 31;
    const long b = (long)blockIdx.x * 8 + (t >> 5);
    const int h = local >> 3, qn = local & 7;
    const long base = b * 512 + h * 16;

    float qv[16];
#pragma unroll
    for (int i = 0; i < 4; ++i) {
        float4 v4 = *(const float4*)(qm + base + qn * 64 + i * 4);
        qv[i * 4 + 0] = v4.x; qv[i * 4 + 1] = v4.y; qv[i * 4 + 2] = v4.z; qv[i * 4 + 3] = v4.w;
    }
    float sc[8];
#pragma unroll
    for (int kn = 0; kn < 8; ++kn) {
        const float* kp = km + base + kn * 64;
        float s = 0.f;
#pragma unroll
        for (int i = 0; i < 4; ++i) {
            float4 v4 = *(const float4*)(kp + i * 4);
            s += qv[i * 4] * v4.x + qv[i * 4 + 1] * v4.y + qv[i * 4 + 2] * v4.z + qv[i * 4 + 3] * v4.w;
        }
        sc[kn] = s * 0.25f;
    }
    float mx = sc[0];
#pragma unroll
    for (int kn = 1; kn < 8; ++kn) mx = fmaxf(mx, sc[kn]);
    float ssum = 0.f;
#pragma unroll
    for (int kn = 0; kn < 8; ++kn) { sc[kn] = expf(sc[kn] - mx); ssum += sc[kn]; }
    float inv = 1.f / ssum;

    float acc[16] = {};
#pragma unroll
    for (int kn = 0; kn < 8; ++kn) {
        float w = sc[kn] * inv;
        const float* vp = vm + base + kn * 64;
#pragma unroll
        for (int i = 0; i < 4; ++i) {
            float4 v4 = *(const float4*)(vp + i * 4);
            acc[i * 4 + 0] += w * v4.x; acc[i * 4 + 1] += w * v4.y;
            acc[i * 4 + 2] += w * v4.z; acc[i * 4 + 3] += w * v4.w;
        }
    }
#pragma unroll
    for (int i = 0; i < 4; ++i) {
        float4 v4 = make_float4(acc[i * 4], acc[i * 4 + 1], acc[i * 4 + 2], acc[i * 4 + 3]);
        *(float4*)(omb + base + qn * 64 + i * 4) = v4;
    }
}

// ---------------------------------------------------------------------------
// Final: att + masked select. hn_mask aliases hnew & mask_w region.
// ---------------------------------------------------------------------------
__global__ __launch_bounds__(256) void final_kernel(
    const float* __restrict__ omb,
    float* hn_mask,
    const float* __restrict__ maskb,
    const float* __restrict__ hx, const float* __restrict__ cx,
    const float* __restrict__ fc_w, const float* __restrict__ fc_b,
    const float* __restrict__ gate_w, const float* __restrict__ gate_b,
    float* __restrict__ hx_out, float* __restrict__ cx_out)
{
    const int o = threadIdx.x;
    const int n = blockIdx.y;
    const long b0 = (long)blockIdx.x * 4;
    __shared__ float oml[4][64];
    {
        int j = threadIdx.x >> 6, d = threadIdx.x & 63;
        oml[j][d] = omb[(b0 + j) * 512 + n * 64 + d];
    }
    __syncthreads();
    float accf[4] = {}, accg[4] = {};
#pragma unroll 4
    for (int d = 0; d < 64; ++d) {
        float wf = fc_w[d * 256 + o];
        float wg = gate_w[d * 256 + o];
#pragma unroll
        for (int j = 0; j < 4; ++j) {
            accf[j] += oml[j][d] * wf;
            accg[j] += oml[j][d] * wg;
        }
    }
    const float fb = fc_b[o], gb = gate_b[o];
#pragma unroll
    for (int j = 0; j < 4; ++j) {
        long b = b0 + j;
        long idx = b * 2048 + (long)n * 256 + o;
        float att = sigmoidf_(accg[j] + gb) * tanhf(accf[j] + fb);
        float h2 = hn_mask[idx] + att;
        float mv = maskb[b * 8 + n];
        hx_out[idx] = (mv != 0.f) ? h2 : hx[idx];
        cx_out[idx] = (mv != 0.f) ? h2 : cx[idx];
        hn_mask[idx] = mv;
    }
}

// ---------------------------------------------------------------------------
extern "C" void kernel_launch(void* const* d_in, const int* in_sizes, int n_in,
                              void* d_out, int out_size, void* d_ws, size_t ws_size,
                              hipStream_t stream)
{
    const float* inp     = (const float*)d_in[0];
    const float* hx      = (const float*)d_in[1];
    const float* cx      = (const float*)d_in[2];
    const float* Wq_i    = (const float*)d_in[4];
    const float* Wk_i    = (const float*)d_in[5];
    const float* Wv_i    = (const float*)d_in[6];
    const float* fc_i_w  = (const float*)d_in[7];
    const float* fc_i_b  = (const float*)d_in[8];
    const float* Wq_m    = (const float*)d_in[9];
    const float* Wk_m    = (const float*)d_in[10];
    const float* Wv_m    = (const float*)d_in[11];
    const float* fc_m_w  = (const float*)d_in[12];
    const float* fc_m_b  = (const float*)d_in[13];
    const float* gate_m_w= (const float*)d_in[14];
    const float* gate_m_b= (const float*)d_in[15];
    const float* Wih     = (const float*)d_in[16];
    const float* Whh     = (const float*)d_in[17];
    const float* bih     = (const float*)d_in[18];
    const float* bhh     = (const float*)d_in[19];

    float* out = (float*)d_out;
    const long BH = (long)B_SZ * NHID_;   // 8388608
    float* hx_out = out;
    float* cx_out = out + BH;
    float* mask_w = out + 2 * BH;
    float* hnew   = mask_w;                     // f32, staged; overwritten by final_kernel
    __hip_bfloat16* hxb = (__hip_bfloat16*)out; // bf16 hx in hx_out region (dead after gru)
    float* qmb = out;                           // (B,8,64) f32, written after gru (hxb dead)
    float* kmb = out + 2097152;
    float* vmb = out + 4194304;

    float* w = (float*)d_ws;
    // persistent small:
    float* a_buf = w;                     // 32768
    float* maskb = w + 32768;             // 32768
    float* cbuf  = w + 65536;             // 6144
    // phase C-E live:
    __hip_bfloat16* wfcb = (__hip_bfloat16*)(w + 131072);   // 2M bf16
    __hip_bfloat16* Whhb = (__hip_bfloat16*)(w + 2228224);  // 1.57M bf16
    __hip_bfloat16* WmT  = (__hip_bfloat16*)(w + 3014656);  // 8*192*256 bf16
    __hip_bfloat16* Wihb = (__hip_bfloat16*)(w + 3276800);  // 6.29M bf16
    __hip_bfloat16* hnewb= (__hip_bfloat16*)(w + 6422528);  // 8.39M bf16
    // phase A-C temporaries (overlaid by Wihb/hnewb later):
    __hip_bfloat16* inpb = (__hip_bfloat16*)(w + 3276800);  // 2M bf16
    __hip_bfloat16* WvT  = (__hip_bfloat16*)(w + 4325376);  // 512K bf16
    __hip_bfloat16* fcT  = (__hip_bfloat16*)(w + 4587520);  // 1M bf16
    __hip_bfloat16* vrowb= (__hip_bfloat16*)(w + 5111808);  // 4M bf16
    float* qbuf = w + 7208960;            // 2M f32
    float* krow = w + 9306112;            // 256K f32
    // phase G:
    float* omb = w + 131072;              // 2M f32 (wfcb dead)

    // ---- Phase A: conversions independent of compute ----
    cb_kernel<<<dim3(6144), dim3(256), 0, stream>>>(fc_i_b, Wih, bih, cbuf);
    f2b_kernel<<<dim3(2048), dim3(256), 0, stream>>>(hx, hxb, 2097152);
    f2b_kernel<<<dim3(1024), dim3(256), 0, stream>>>(inp, inpb, 524288);
    tconv_kernel<<<dim3(32, 16, 1), dim3(256), 0, stream>>>(
        Wv_i + 512 * 1024, 1024, 0, WvT, 512, 0);
    tconv_kernel<<<dim3(32, 32, 1), dim3(256), 0, stream>>>(
        fc_i_w, 1024, 0, fcT, 1024, 0);
    // ---- Phase B: mask path (fp32) ----
    gemm_nn<<<dim3(1, 64, 1), dim3(256), 0, stream>>>(
        inp, Wk_i + 512 * 64, krow, 4096, 64, 512, 512, 64, 64, 0, 0, 0);
    gemm_nn<<<dim3(1, 64, 8), dim3(256), 0, stream>>>(
        hx, Wq_i, qbuf, 4096, 64, 256, 2048, 64, 512, 256, 16384, 64);
    s1_mask_kernel<<<dim3(1024), dim3(256), 0, stream>>>(qbuf, krow, a_buf, maskb);
    // vrowb = inpb @ WvT^T   (4096x1024, K=512)
    gemm_mfma_obf16<<<dim3(16, 32, 1), dim3(256), 0, stream>>>(
        inpb, 512, WvT, 512, vrowb, 1024, 512);
    // ---- Phase C: wfcb = vrowb @ fcT^T (4096x1024, K=1024) ----
    gemm_mfma_obf16<<<dim3(16, 32, 1), dim3(256), 0, stream>>>(
        vrowb, 1024, fcT, 1024, wfcb, 1024, 1024);
    // ---- Phase D: weight conversions (overlay dead temporaries) ----
    f2b_kernel<<<dim3(2048), dim3(256), 0, stream>>>(Wih, Wihb, 1572864);
    f2b_kernel<<<dim3(1024), dim3(256), 0, stream>>>(Whh, Whhb, 393216);
    tconv_kernel<<<dim3(2, 8, 8), dim3(256), 0, stream>>>(
        Wq_m, 64, 16384, WmT, 256, 49152);
    tconv_kernel<<<dim3(2, 8, 8), dim3(256), 0, stream>>>(
        Wk_m, 64, 16384, WmT + 64 * 256, 256, 49152);
    tconv_kernel<<<dim3(2, 8, 8), dim3(256), 0, stream>>>(
        Wv_m, 64, 16384, WmT + 128 * 256, 256, 49152);
    // ---- Phase E: fused MFMA GEMM + GRU -> hnew (f32) + hnewb (bf16) ----
    gru_fused_mfma<<<dim3(8, 32, 8), dim3(256), 0, stream>>>(
        wfcb, hxb, hx, a_buf, cbuf, Wihb, Whhb, bhh, hnew, hnewb);
    // ---- Phase F: fused q/k/v_m projections -> hx_out region ----
    gemm_mfma_qkv<<<dim3(3, 32, 8), dim3(256), 0, stream>>>(hnewb, WmT, qmb);
    // ---- Phase G: memory attention + final ----
    mattn_kernel<<<dim3(512), dim3(256), 0, stream>>>(qmb, kmb, vmb, omb);
    final_kernel<<<dim3(1024, 8), dim3(256), 0, stream>>>(
        omb, hnew, maskb, hx, cx, fc_m_w, fc_m_b, gate_m_w, gate_m_b, hx_out, cx_out);
}

// Round 6
// 290.982 us; speedup vs baseline: 5.4844x; 1.1285x over previous
//
#include <hip/hip_runtime.h>
#include <hip/hip_bf16.h>

#define B_SZ 4096
#define NHID_ 2048

typedef __bf16 bf16x8 __attribute__((ext_vector_type(8)));
typedef float f32x4 __attribute__((ext_vector_type(4)));

__device__ __forceinline__ float sigmoidf_(float x) { return 1.f / (1.f + expf(-x)); }
__device__ __forceinline__ float b2f_(unsigned short u) {
    unsigned v = (unsigned)u << 16;
    return __builtin_bit_cast(float, v);
}

#define GLDS16(gp, lp) __builtin_amdgcn_global_load_lds( \
    (const __attribute__((address_space(1))) void*)(gp), \
    (__attribute__((address_space(3))) void*)(lp), 16, 0, 0)

// ---------------------------------------------------------------------------
// fp32 -> bf16 conversion, 4 elems/thread, grid-stride
// ---------------------------------------------------------------------------
__global__ __launch_bounds__(256) void f2b_kernel(
    const float* __restrict__ src, __hip_bfloat16* __restrict__ dst, long n4)
{
    long i = (long)blockIdx.x * 256 + threadIdx.x;
    const long stride = (long)gridDim.x * 256;
    for (; i < n4; i += stride) {
        float4 v = ((const float4*)src)[i];
        __hip_bfloat16 b0 = __float2bfloat16(v.x);
        __hip_bfloat16 b1 = __float2bfloat16(v.y);
        __hip_bfloat16 b2 = __float2bfloat16(v.z);
        __hip_bfloat16 b3 = __float2bfloat16(v.w);
        ushort4 u;
        u.x = *(unsigned short*)&b0; u.y = *(unsigned short*)&b1;
        u.z = *(unsigned short*)&b2; u.w = *(unsigned short*)&b3;
        ((ushort4*)dst)[i] = u;
    }
}

// ---------------------------------------------------------------------------
// Wih convert + cb: Wihb = bf16(Wih); cb[j] = dot(fc_i_b, Wih[j,:]) + bih[j]
// ---------------------------------------------------------------------------
__global__ __launch_bounds__(256) void wih_prep(
    const float* __restrict__ Wih, const float* __restrict__ fc_i_b,
    const float* __restrict__ bih, __hip_bfloat16* __restrict__ Wihb,
    float* __restrict__ cb)
{
    long j = blockIdx.x;
    const float* row = Wih + j * 1024;
    __hip_bfloat16* drow = Wihb + j * 1024;
    int i = threadIdx.x * 4;
    float4 v = *(const float4*)(row + i);
    __hip_bfloat16 b0 = __float2bfloat16(v.x);
    __hip_bfloat16 b1 = __float2bfloat16(v.y);
    __hip_bfloat16 b2 = __float2bfloat16(v.z);
    __hip_bfloat16 b3 = __float2bfloat16(v.w);
    ushort4 u;
    u.x = *(unsigned short*)&b0; u.y = *(unsigned short*)&b1;
    u.z = *(unsigned short*)&b2; u.w = *(unsigned short*)&b3;
    *(ushort4*)(drow + i) = u;
    float s = fc_i_b[i] * v.x + fc_i_b[i + 1] * v.y +
              fc_i_b[i + 2] * v.z + fc_i_b[i + 3] * v.w;
#pragma unroll
    for (int off = 32; off > 0; off >>= 1) s += __shfl_xor(s, off, 64);
    __shared__ float red[4];
    if ((threadIdx.x & 63) == 0) red[threadIdx.x >> 6] = s;
    __syncthreads();
    if (threadIdx.x == 0) cb[j] = red[0] + red[1] + red[2] + red[3] + bih[j];
}

// ---------------------------------------------------------------------------
// Transpose + convert: dst[c*ldd + r] (bf16) = src[r*C + c] (f32), batched z.
// ---------------------------------------------------------------------------
__global__ __launch_bounds__(256) void tconv_kernel(
    const float* __restrict__ src, int C, long sS,
    __hip_bfloat16* __restrict__ dst, int ldd, long sD)
{
    src += (long)blockIdx.z * sS;
    dst += (long)blockIdx.z * sD;
    const int r0 = blockIdx.y * 32, c0 = blockIdx.x * 32;
    const int tx = threadIdx.x & 31, ty = threadIdx.x >> 5;
    __shared__ float tile[32][33];
#pragma unroll
    for (int i = 0; i < 4; ++i)
        tile[ty + i * 8][tx] = src[(long)(r0 + ty + i * 8) * C + c0 + tx];
    __syncthreads();
#pragma unroll
    for (int i = 0; i < 4; ++i)
        dst[(long)(c0 + ty + i * 8) * ldd + r0 + tx] = __float2bfloat16(tile[tx][ty + i * 8]);
}

// ---------------------------------------------------------------------------
// Build fcgT (512 x 64): rows 32t+[0..15] = fc_m_w cols 16t..16t+15 (transposed),
// rows 32t+[16..31] = gate_m_w same cols.
// ---------------------------------------------------------------------------
__global__ __launch_bounds__(256) void fcg_prep(
    const float* __restrict__ fc_w, const float* __restrict__ gate_w,
    __hip_bfloat16* __restrict__ fcgT)
{
    int tid = blockIdx.x * 256 + threadIdx.x;  // 32768
    int np = tid >> 6, k = tid & 63;
    int o = (np >> 5) * 16 + (np & 15);
    const float* src = ((np >> 4) & 1) ? gate_w : fc_w;
    fcgT[tid] = __float2bfloat16(src[k * 256 + o]);
}

// ---------------------------------------------------------------------------
// Generic fp32 tiled GEMM (mask-precision-critical helpers only)
// ---------------------------------------------------------------------------
#define GM_BM 64
#define GM_BN 64
#define GM_BK 16

__global__ __launch_bounds__(256) void gemm_nn(
    const float* __restrict__ A, const float* __restrict__ Bm, float* __restrict__ C,
    int M, int N, int K, int lda, int ldb, int ldc,
    long sA, long sB, long sC)
{
    const int z = blockIdx.z;
    A += (long)z * sA; Bm += (long)z * sB; C += (long)z * sC;
    const int m0 = blockIdx.y * GM_BM;
    const int n0 = blockIdx.x * GM_BN;
    const int tid = threadIdx.x;
    const int tx = tid & 15;
    const int ty = tid >> 4;

    __shared__ float As[GM_BK][GM_BM + 4];
    __shared__ float Bs[GM_BK][GM_BN + 4];

    float acc[4][4] = {};

    for (int k0 = 0; k0 < K; k0 += GM_BK) {
#pragma unroll
        for (int i = 0; i < 4; ++i) {
            int idx = tid + i * 256;
            int r = idx >> 4, c = idx & 15;
            As[c][r] = A[(long)(m0 + r) * lda + k0 + c];
        }
#pragma unroll
        for (int i = 0; i < 4; ++i) {
            int idx = tid + i * 256;
            int r = idx >> 6, c = idx & 63;
            Bs[r][c] = Bm[(long)(k0 + r) * ldb + n0 + c];
        }
        __syncthreads();
#pragma unroll
        for (int kk = 0; kk < GM_BK; ++kk) {
            float4 a4 = *(const float4*)&As[kk][ty * 4];
            float4 b4 = *(const float4*)&Bs[kk][tx * 4];
            float av[4] = {a4.x, a4.y, a4.z, a4.w};
            float bv[4] = {b4.x, b4.y, b4.z, b4.w};
#pragma unroll
            for (int i = 0; i < 4; ++i)
#pragma unroll
                for (int j = 0; j < 4; ++j)
                    acc[i][j] += av[i] * bv[j];
        }
        __syncthreads();
    }
#pragma unroll
    for (int i = 0; i < 4; ++i) {
        long m = m0 + ty * 4 + i;
#pragma unroll
        for (int j = 0; j < 4; ++j) {
            int n = n0 + tx * 4 + j;
            C[m * ldc + n] = acc[i][j];
        }
    }
}

// ---------------------------------------------------------------------------
// MFMA GEMM: C(bf16, MxN) = A(bf16, MxK, lda) @ BT(bf16, NxK, ldb)^T
// ---------------------------------------------------------------------------
__global__ __launch_bounds__(256) void gemm_mfma_obf16(
    const __hip_bfloat16* __restrict__ A, int lda,
    const __hip_bfloat16* __restrict__ BT, int ldb,
    __hip_bfloat16* __restrict__ C, int ldc, int K)
{
    const int m0 = blockIdx.y * 128;
    const int n0 = blockIdx.x * 64;
    const int tid = threadIdx.x;
    const int lane = tid & 63, wid = tid >> 6;
    const int wr = wid >> 1, wc = wid & 1;
    const int l15 = lane & 15, l4 = lane >> 4;

    __shared__ __align__(16) char lds_raw[16384 + 8192];
    char* Alds = lds_raw;
    char* Blds = lds_raw + 16384;

    f32x4 acc[4][2] = {};

    for (int k0 = 0; k0 < K; k0 += 64) {
#pragma unroll
        for (int ii = 0; ii < 4; ++ii) {
            int issue = ii * 4 + wid;
            int chunk = issue * 64 + lane;
            int r = chunk >> 3, cs = chunk & 7;
            int cl = cs ^ (r & 7);
            const __hip_bfloat16* g = A + (long)(m0 + r) * lda + k0 + cl * 8;
            GLDS16(g, Alds + issue * 1024);
        }
#pragma unroll
        for (int jj = 0; jj < 2; ++jj) {
            int issue = jj * 4 + wid;
            int chunk = issue * 64 + lane;
            int r = chunk >> 3, cs = chunk & 7;
            int cl = cs ^ (r & 7);
            const __hip_bfloat16* g = BT + (long)(n0 + r) * ldb + k0 + cl * 8;
            GLDS16(g, Blds + issue * 1024);
        }
        __syncthreads();
#pragma unroll
        for (int kk = 0; kk < 2; ++kk) {
            bf16x8 af[4], bfr[2];
#pragma unroll
            for (int im = 0; im < 4; ++im) {
                int r = wr * 64 + im * 16 + l15;
                int cl = (kk * 4 + l4) ^ (l15 & 7);
                af[im] = *(const bf16x8*)(Alds + r * 128 + cl * 16);
            }
#pragma unroll
            for (int jn = 0; jn < 2; ++jn) {
                int r = wc * 32 + jn * 16 + l15;
                int cl = (kk * 4 + l4) ^ (l15 & 7);
                bfr[jn] = *(const bf16x8*)(Blds + r * 128 + cl * 16);
            }
#pragma unroll
            for (int im = 0; im < 4; ++im)
#pragma unroll
                for (int jn = 0; jn < 2; ++jn)
                    acc[im][jn] = __builtin_amdgcn_mfma_f32_16x16x32_bf16(
                        af[im], bfr[jn], acc[im][jn], 0, 0, 0);
        }
        __syncthreads();
    }
#pragma unroll
    for (int im = 0; im < 4; ++im)
#pragma unroll
        for (int reg = 0; reg < 4; ++reg) {
            long m = m0 + wr * 64 + im * 16 + l4 * 4 + reg;
#pragma unroll
            for (int jn = 0; jn < 2; ++jn) {
                int n = n0 + wc * 32 + jn * 16 + l15;
                C[m * ldc + n] = __float2bfloat16(acc[im][jn][reg]);
            }
        }
}

// ---------------------------------------------------------------------------
// Fused q/k/v_m projections (bf16 out). Per z: C = hnewb[:,z*256:+256] @ WmT[z]^T
// cols 0:64->qmb, 64:128->kmb, 128:192->vmb (each (B,8,64) bf16).
// ---------------------------------------------------------------------------
__global__ __launch_bounds__(256) void gemm_mfma_qkv(
    const __hip_bfloat16* __restrict__ hnewb,  // (B,2048)
    const __hip_bfloat16* __restrict__ WmT,    // (8,192,256)
    __hip_bfloat16* __restrict__ qout)         // q|k|v, each 2097152 bf16
{
    const int z = blockIdx.z;
    const int m0 = blockIdx.y * 128;
    const int n0 = blockIdx.x * 64;
    const int tid = threadIdx.x;
    const int lane = tid & 63, wid = tid >> 6;
    const int wr = wid >> 1, wc = wid & 1;
    const int l15 = lane & 15, l4 = lane >> 4;

    const __hip_bfloat16* A = hnewb + z * 256;
    const __hip_bfloat16* BT = WmT + (long)z * 192 * 256;

    __shared__ __align__(16) char lds_raw[16384 + 8192];
    char* Alds = lds_raw;
    char* Blds = lds_raw + 16384;

    f32x4 acc[4][2] = {};

    for (int k0 = 0; k0 < 256; k0 += 64) {
#pragma unroll
        for (int ii = 0; ii < 4; ++ii) {
            int issue = ii * 4 + wid;
            int chunk = issue * 64 + lane;
            int r = chunk >> 3, cs = chunk & 7;
            int cl = cs ^ (r & 7);
            const __hip_bfloat16* g = A + (long)(m0 + r) * 2048 + k0 + cl * 8;
            GLDS16(g, Alds + issue * 1024);
        }
#pragma unroll
        for (int jj = 0; jj < 2; ++jj) {
            int issue = jj * 4 + wid;
            int chunk = issue * 64 + lane;
            int r = chunk >> 3, cs = chunk & 7;
            int cl = cs ^ (r & 7);
            const __hip_bfloat16* g = BT + (long)(n0 + r) * 256 + k0 + cl * 8;
            GLDS16(g, Blds + issue * 1024);
        }
        __syncthreads();
#pragma unroll
        for (int kk = 0; kk < 2; ++kk) {
            bf16x8 af[4], bfr[2];
#pragma unroll
            for (int im = 0; im < 4; ++im) {
                int r = wr * 64 + im * 16 + l15;
                int cl = (kk * 4 + l4) ^ (l15 & 7);
                af[im] = *(const bf16x8*)(Alds + r * 128 + cl * 16);
            }
#pragma unroll
            for (int jn = 0; jn < 2; ++jn) {
                int r = wc * 32 + jn * 16 + l15;
                int cl = (kk * 4 + l4) ^ (l15 & 7);
                bfr[jn] = *(const bf16x8*)(Blds + r * 128 + cl * 16);
            }
#pragma unroll
            for (int im = 0; im < 4; ++im)
#pragma unroll
                for (int jn = 0; jn < 2; ++jn)
                    acc[im][jn] = __builtin_amdgcn_mfma_f32_16x16x32_bf16(
                        af[im], bfr[jn], acc[im][jn], 0, 0, 0);
        }
        __syncthreads();
    }
#pragma unroll
    for (int jn = 0; jn < 2; ++jn) {
        int j = n0 + wc * 32 + jn * 16 + l15;   // [0,192)
        int g = j >> 6, d = j & 63;
        __hip_bfloat16* outp = qout + (long)g * 2097152 + (long)z * 64 + d;
#pragma unroll
        for (int im = 0; im < 4; ++im)
#pragma unroll
            for (int reg = 0; reg < 4; ++reg) {
                long m = m0 + wr * 64 + im * 16 + l4 * 4 + reg;
                outp[m * 512] = __float2bfloat16(acc[im][jn][reg]);
            }
    }
}

// ---------------------------------------------------------------------------
// s1 / sigmoid(s1) / top-k mask (fp32 — rank decisions are precision-critical)
// ---------------------------------------------------------------------------
__global__ __launch_bounds__(256) void s1_mask_kernel(
    const float* __restrict__ qbuf, const float* __restrict__ krow,
    float* __restrict__ a_buf, float* __restrict__ mask_buf)
{
    const int wave = threadIdx.x >> 6;
    const int lane = threadIdx.x & 63;
    const long b = (long)blockIdx.x * 4 + wave;
    const float kr = krow[b * 64 + lane];
    float s1v[8];
#pragma unroll
    for (int n = 0; n < 8; ++n) {
        float p = qbuf[b * 512 + n * 64 + lane] * kr;
#pragma unroll
        for (int off = 32; off > 0; off >>= 1) p += __shfl_xor(p, off, 64);
        s1v[n] = p * 0.125f;
    }
    unsigned maskbits = 0;
#pragma unroll
    for (int n = 0; n < 8; ++n) {
        int rank = 0;
#pragma unroll
        for (int m = 0; m < 8; ++m) {
            if (m == n) continue;
            if (s1v[m] < s1v[n] || (s1v[m] == s1v[n] && m < n)) rank++;
        }
        if (rank >= 4) maskbits |= (1u << n);
    }
    if (lane < 8) {
        float sv = s1v[0];
#pragma unroll
        for (int n = 1; n < 8; ++n)
            if (lane == n) sv = s1v[n];
        a_buf[b * 8 + lane] = sigmoidf_(sv);
        mask_buf[b * 8 + lane] = ((maskbits >> lane) & 1u) ? 1.0f : 0.0f;
    }
}

// ---------------------------------------------------------------------------
// MFMA big GEMM + fused GRU epilogue. 1-D grid, XCD-pinned: kblk = bid&7.
// ---------------------------------------------------------------------------
__global__ __launch_bounds__(256) void gru_fused_mfma(
    const __hip_bfloat16* __restrict__ wfcb,   // (B,1024)
    const __hip_bfloat16* __restrict__ hxb,    // (B,2048)
    const float* __restrict__ a_buf,           // (B,8)
    const float* __restrict__ cb,              // (8,768)
    const __hip_bfloat16* __restrict__ Wihb,   // (8,768,1024)
    const __hip_bfloat16* __restrict__ Whhb,   // (8,768,256)
    const float* __restrict__ bhh,             // (8,768)
    __hip_bfloat16* __restrict__ hnewb)        // (B,2048)
{
    const int bid = blockIdx.x;
    const int kblk = bid & 7;
    const int r_ = bid >> 3;
    const int ol0 = (r_ & 7) * 32;
    const int m0 = (r_ >> 3) * 128;
    const int tid = threadIdx.x;
    const int lane = tid & 63, wid = tid >> 6;
    const int wr = wid >> 1, wc = wid & 1;
    const int l15 = lane & 15, l4 = lane >> 4;

    __shared__ __align__(16) char lds_raw[16384 + 12288];
    char* Alds = lds_raw;
    char* Blds = lds_raw + 16384;

    f32x4 accx[4][3] = {};
    f32x4 acch[4][3] = {};

#define STAGE(Asrc, sA, Bsrc, sB, k0) do {                                     \
    _Pragma("unroll") for (int ii = 0; ii < 4; ++ii) {                         \
        int issue = ii * 4 + wid;                                              \
        int chunk = issue * 64 + lane;                                         \
        int r = chunk >> 3, cs = chunk & 7;                                    \
        int cl = cs ^ (r & 7);                                                 \
        const __hip_bfloat16* g = (Asrc) + (long)(m0 + r) * (sA) + (k0) + cl * 8; \
        GLDS16(g, Alds + issue * 1024);                                        \
    }                                                                          \
    _Pragma("unroll") for (int jj = 0; jj < 3; ++jj) {                         \
        int issue = jj * 4 + wid;                                              \
        int chunk = issue * 64 + lane;                                         \
        int r = chunk >> 3, cs = chunk & 7;                                    \
        int cl = cs ^ (r & 7);                                                 \
        int gg = r >> 5, oll = r & 31;                                         \
        const __hip_bfloat16* g = (Bsrc) + (long)(gg * 256 + ol0 + oll) * (sB) + (k0) + cl * 8; \
        GLDS16(g, Blds + issue * 1024);                                        \
    }                                                                          \
} while (0)

#define COMPUTE(acc) do {                                                      \
    _Pragma("unroll") for (int kk = 0; kk < 2; ++kk) {                         \
        bf16x8 af[4], bfr[3];                                                  \
        _Pragma("unroll") for (int im = 0; im < 4; ++im) {                     \
            int r = wr * 64 + im * 16 + l15;                                   \
            int cl = (kk * 4 + l4) ^ (l15 & 7);                                \
            af[im] = *(const bf16x8*)(Alds + r * 128 + cl * 16);               \
        }                                                                      \
        _Pragma("unroll") for (int g = 0; g < 3; ++g) {                        \
            int r = g * 32 + wc * 16 + l15;                                    \
            int cl = (kk * 4 + l4) ^ (l15 & 7);                                \
            bfr[g] = *(const bf16x8*)(Blds + r * 128 + cl * 16);               \
        }                                                                      \
        _Pragma("unroll") for (int im = 0; im < 4; ++im)                       \
            _Pragma("unroll") for (int g = 0; g < 3; ++g)                      \
                acc[im][g] = __builtin_amdgcn_mfma_f32_16x16x32_bf16(          \
                    af[im], bfr[g], acc[im][g], 0, 0, 0);                      \
    }                                                                          \
} while (0)

    const __hip_bfloat16* Wk = Wihb + (long)kblk * 768 * 1024;
    for (int k0 = 0; k0 < 1024; k0 += 64) {
        STAGE(wfcb, 1024, Wk, 1024, k0);
        __syncthreads();
        COMPUTE(accx);
        __syncthreads();
    }
    const __hip_bfloat16* Wh = Whhb + (long)kblk * 768 * 256;
    const __hip_bfloat16* hxk = hxb + kblk * 256;
    for (int k0 = 0; k0 < 256; k0 += 64) {
        STAGE(hxk, 2048, Wh, 256, k0);
        __syncthreads();
        COMPUTE(acch);
        __syncthreads();
    }
#undef STAGE
#undef COMPUTE

    const int ol = ol0 + wc * 16 + l15;
    const float* cbk = cb + kblk * 768;
    const float cb0 = cbk[ol], cb1 = cbk[256 + ol], cb2 = cbk[512 + ol];
    const float* bhk = bhh + kblk * 768;
    const float bh0 = bhk[ol], bh1 = bhk[256 + ol], bh2 = bhk[512 + ol];
#pragma unroll
    for (int im = 0; im < 4; ++im) {
#pragma unroll
        for (int reg = 0; reg < 4; ++reg) {
            long m = m0 + wr * 64 + im * 16 + l4 * 4 + reg;
            float av = a_buf[m * 8 + kblk];
            float gx0 = av * accx[im][0][reg] + cb0;
            float gx1 = av * accx[im][1][reg] + cb1;
            float gx2 = av * accx[im][2][reg] + cb2;
            float gh0 = acch[im][0][reg] + bh0;
            float gh1 = acch[im][1][reg] + bh1;
            float gh2 = acch[im][2][reg] + bh2;
            float rr = sigmoidf_(gx0 + gh0);
            float zz = sigmoidf_(gx1 + gh1);
            float nn = tanhf(gx2 + rr * gh2);
            long idx = m * 2048 + kblk * 256 + ol;
            float hxv = __bfloat162float(hxb[idx]);
            hnewb[idx] = __float2bfloat16((1.f - zz) * nn + zz * hxv);
        }
    }
}

// ---------------------------------------------------------------------------
// Memory attention (bf16 in/out)
// ---------------------------------------------------------------------------
__global__ __launch_bounds__(256) void mattn_kernel(
    const __hip_bfloat16* __restrict__ qm, const __hip_bfloat16* __restrict__ km,
    const __hip_bfloat16* __restrict__ vm, __hip_bfloat16* __restrict__ omb)
{
    const int t = threadIdx.x;
    const int local = t & 31;
    const long b = (long)blockIdx.x * 8 + (t >> 5);
    const int h = local >> 3, qn = local & 7;
    const long base = b * 512 + h * 16;

    float qv[16];
#pragma unroll
    for (int i = 0; i < 2; ++i) {
        bf16x8 v = *(const bf16x8*)(qm + base + qn * 64 + i * 8);
#pragma unroll
        for (int j = 0; j < 8; ++j) qv[i * 8 + j] = (float)v[j];
    }
    float sc[8];
#pragma unroll
    for (int kn = 0; kn < 8; ++kn) {
        float s = 0.f;
#pragma unroll
        for (int i = 0; i < 2; ++i) {
            bf16x8 v = *(const bf16x8*)(km + base + kn * 64 + i * 8);
#pragma unroll
            for (int j = 0; j < 8; ++j) s += qv[i * 8 + j] * (float)v[j];
        }
        sc[kn] = s * 0.25f;
    }
    float mx = sc[0];
#pragma unroll
    for (int kn = 1; kn < 8; ++kn) mx = fmaxf(mx, sc[kn]);
    float ssum = 0.f;
#pragma unroll
    for (int kn = 0; kn < 8; ++kn) { sc[kn] = expf(sc[kn] - mx); ssum += sc[kn]; }
    float inv = 1.f / ssum;

    float acc[16] = {};
#pragma unroll
    for (int kn = 0; kn < 8; ++kn) {
        float w = sc[kn] * inv;
#pragma unroll
        for (int i = 0; i < 2; ++i) {
            bf16x8 v = *(const bf16x8*)(vm + base + kn * 64 + i * 8);
#pragma unroll
            for (int j = 0; j < 8; ++j) acc[i * 8 + j] += w * (float)v[j];
        }
    }
#pragma unroll
    for (int i = 0; i < 2; ++i) {
        bf16x8 o;
#pragma unroll
        for (int j = 0; j < 8; ++j) o[j] = (__bf16)acc[i * 8 + j];
        *(bf16x8*)(omb + base + qn * 64 + i * 8) = o;
    }
}

// ---------------------------------------------------------------------------
// att GEMM: (32768 x 64) om @ fcgT(512x64)^T with fused sig*tanh epilogue.
// jn=0 frag = fc cols, jn=1 frag = gate cols for the SAME o's.
// ---------------------------------------------------------------------------
__global__ __launch_bounds__(256) void att_gemm(
    const __hip_bfloat16* __restrict__ omb,    // (32768,64)
    const __hip_bfloat16* __restrict__ fcgT,   // (512,64)
    const float* __restrict__ fc_b, const float* __restrict__ gate_b,
    __hip_bfloat16* __restrict__ attb)         // (32768,256) == (B,2048)
{
    const int m0 = blockIdx.y * 128;
    const int n0 = blockIdx.x * 64;
    const int tid = threadIdx.x;
    const int lane = tid & 63, wid = tid >> 6;
    const int wr = wid >> 1, wc = wid & 1;
    const int l15 = lane & 15, l4 = lane >> 4;

    __shared__ __align__(16) char lds_raw[16384 + 8192];
    char* Alds = lds_raw;
    char* Blds = lds_raw + 16384;

    f32x4 acc[4][2] = {};
#pragma unroll
    for (int ii = 0; ii < 4; ++ii) {
        int issue = ii * 4 + wid;
        int chunk = issue * 64 + lane;
        int r = chunk >> 3, cs = chunk & 7;
        int cl = cs ^ (r & 7);
        const __hip_bfloat16* g = omb + (long)(m0 + r) * 64 + cl * 8;
        GLDS16(g, Alds + issue * 1024);
    }
#pragma unroll
    for (int jj = 0; jj < 2; ++jj) {
        int issue = jj * 4 + wid;
        int chunk = issue * 64 + lane;
        int r = chunk >> 3, cs = chunk & 7;
        int cl = cs ^ (r & 7);
        const __hip_bfloat16* g = fcgT + (long)(n0 + r) * 64 + cl * 8;
        GLDS16(g, Blds + issue * 1024);
    }
    __syncthreads();
#pragma unroll
    for (int kk = 0; kk < 2; ++kk) {
        bf16x8 af[4], bfr[2];
#pragma unroll
        for (int im = 0; im < 4; ++im) {
            int r = wr * 64 + im * 16 + l15;
            int cl = (kk * 4 + l4) ^ (l15 & 7);
            af[im] = *(const bf16x8*)(Alds + r * 128 + cl * 16);
        }
#pragma unroll
        for (int jn = 0; jn < 2; ++jn) {
            int r = wc * 32 + jn * 16 + l15;
            int cl = (kk * 4 + l4) ^ (l15 & 7);
            bfr[jn] = *(const bf16x8*)(Blds + r * 128 + cl * 16);
        }
#pragma unroll
        for (int im = 0; im < 4; ++im)
#pragma unroll
            for (int jn = 0; jn < 2; ++jn)
                acc[im][jn] = __builtin_amdgcn_mfma_f32_16x16x32_bf16(
                    af[im], bfr[jn], acc[im][jn], 0, 0, 0);
    }
    const int o = ((n0 + wc * 32) >> 1) + l15;
    const float fb = fc_b[o], gb = gate_b[o];
#pragma unroll
    for (int im = 0; im < 4; ++im)
#pragma unroll
        for (int reg = 0; reg < 4; ++reg) {
            long m = m0 + wr * 64 + im * 16 + l4 * 4 + reg;
            float att = sigmoidf_(acc[im][1][reg] + gb) * tanhf(acc[im][0][reg] + fb);
            attb[m * 256 + o] = __float2bfloat16(att);
        }
}

// ---------------------------------------------------------------------------
// Final elementwise: h2 = hnewb + attb; masked select; mask_w write.
// ---------------------------------------------------------------------------
__global__ __launch_bounds__(256) void final_elem(
    const __hip_bfloat16* __restrict__ hnewb, const __hip_bfloat16* __restrict__ attb,
    const float* __restrict__ maskb,
    const float* __restrict__ hx, const float* __restrict__ cx,
    float* __restrict__ hx_out, float* __restrict__ cx_out, float* __restrict__ mask_w)
{
    long i4 = (long)blockIdx.x * 256 + threadIdx.x;   // 2,097,152 quads
    long e = i4 * 4;
    int n = (int)((e >> 8) & 7);
    long b = e >> 11;
    float mv = maskb[b * 8 + n];
    ushort4 hn = ((const ushort4*)hnewb)[i4];
    ushort4 at = ((const ushort4*)attb)[i4];
    float4 hxv = ((const float4*)hx)[i4];
    float4 cxv = ((const float4*)cx)[i4];
    float4 h2;
    h2.x = b2f_(hn.x) + b2f_(at.x);
    h2.y = b2f_(hn.y) + b2f_(at.y);
    h2.z = b2f_(hn.z) + b2f_(at.z);
    h2.w = b2f_(hn.w) + b2f_(at.w);
    bool k = (mv != 0.f);
    float4 ho = k ? h2 : hxv;
    float4 co = k ? h2 : cxv;
    ((float4*)hx_out)[i4] = ho;
    ((float4*)cx_out)[i4] = co;
    ((float4*)mask_w)[i4] = make_float4(mv, mv, mv, mv);
}

// ---------------------------------------------------------------------------
extern "C" void kernel_launch(void* const* d_in, const int* in_sizes, int n_in,
                              void* d_out, int out_size, void* d_ws, size_t ws_size,
                              hipStream_t stream)
{
    const float* inp     = (const float*)d_in[0];
    const float* hx      = (const float*)d_in[1];
    const float* cx      = (const float*)d_in[2];
    const float* Wq_i    = (const float*)d_in[4];
    const float* Wk_i    = (const float*)d_in[5];
    const float* Wv_i    = (const float*)d_in[6];
    const float* fc_i_w  = (const float*)d_in[7];
    const float* fc_i_b  = (const float*)d_in[8];
    const float* Wq_m    = (const float*)d_in[9];
    const float* Wk_m    = (const float*)d_in[10];
    const float* Wv_m    = (const float*)d_in[11];
    const float* fc_m_w  = (const float*)d_in[12];
    const float* fc_m_b  = (const float*)d_in[13];
    const float* gate_m_w= (const float*)d_in[14];
    const float* gate_m_b= (const float*)d_in[15];
    const float* Wih     = (const float*)d_in[16];
    const float* Whh     = (const float*)d_in[17];
    const float* bih     = (const float*)d_in[18];
    const float* bhh     = (const float*)d_in[19];

    float* out = (float*)d_out;
    const long BH = (long)B_SZ * NHID_;   // 8388608
    float* hx_out = out;
    float* cx_out = out + BH;
    float* mask_w = out + 2 * BH;
    __hip_bfloat16* hxb = (__hip_bfloat16*)out;   // bf16 hx in hx_out region (dead after gru)
    __hip_bfloat16* qkvb = (__hip_bfloat16*)out;  // q|k|v bf16, written post-gru

    // Workspace layout (float offsets; all sizes exact):
    float* w = (float*)d_ws;
    float* a_buf = w;                                        // [0, 32768)
    float* maskb = w + 32768;                                // [32768, 65536)
    float* cbuf  = w + 65536;                                // [65536, 71680)
    __hip_bfloat16* fcgT = (__hip_bfloat16*)(w + 73728);     // 32768 bf16   -> [73728, 90112)
    __hip_bfloat16* WmT  = (__hip_bfloat16*)(w + 90112);     // 393216 bf16  -> [90112, 286720)
    __hip_bfloat16* Wihb = (__hip_bfloat16*)(w + 286720);    // 6291456 bf16 -> [286720, 3432448)
    __hip_bfloat16* Whhb = (__hip_bfloat16*)(w + 3432448);   // 1572864 bf16 -> [3432448, 4218880)
    __hip_bfloat16* wfcb = (__hip_bfloat16*)(w + 4218880);   // 4194304 bf16 -> [4218880, 6316032)  FULL SIZE
    __hip_bfloat16* hnewb= (__hip_bfloat16*)(w + 6316032);   // 8388608 bf16 -> [6316032, 10510336)
    // pre-gru overlays inside hnewb's region (all dead before gru writes hnewb):
    float* qbuf = w + 6316032;                               // [6316032, 8413184)
    float* krow = w + 8413184;                               // [8413184, 8675328)
    __hip_bfloat16* inpb = (__hip_bfloat16*)(w + 8675328);   // 2097152 bf16 -> [8675328, 9723904)
    __hip_bfloat16* WvB  = (__hip_bfloat16*)(w + 9723904);   // 524288 bf16  -> [9723904, 9986048)
    __hip_bfloat16* fcT  = (__hip_bfloat16*)(w + 9986048);   // 1048576 bf16 -> [9986048, 10510336)
    __hip_bfloat16* WvFT = (__hip_bfloat16*)(w + 10510336);  // 524288 bf16  -> [10510336, 10772480)
    // post-gru overlays (Wihb/Whhb/wfcb dead):
    __hip_bfloat16* omb  = (__hip_bfloat16*)(w + 286720);    // 2097152 bf16 -> [286720, 1335296)
    __hip_bfloat16* attb = (__hip_bfloat16*)(w + 1335296);   // 8388608 bf16 -> [1335296, 5529600)

    // ---- Phase A: conversions / prep ----
    wih_prep<<<dim3(6144), dim3(256), 0, stream>>>(Wih, fc_i_b, bih, Wihb, cbuf);
    f2b_kernel<<<dim3(2048), dim3(256), 0, stream>>>(hx, hxb, 2097152);
    f2b_kernel<<<dim3(1024), dim3(256), 0, stream>>>(inp, inpb, 524288);
    f2b_kernel<<<dim3(1024), dim3(256), 0, stream>>>(Whh, Whhb, 393216);
    f2b_kernel<<<dim3(512), dim3(256), 0, stream>>>(Wv_i + 512 * 1024, WvB, 131072);
    tconv_kernel<<<dim3(32, 32, 1), dim3(256), 0, stream>>>(fc_i_w, 1024, 0, fcT, 1024, 0);
    tconv_kernel<<<dim3(2, 8, 8), dim3(256), 0, stream>>>(Wq_m, 64, 16384, WmT, 256, 49152);
    tconv_kernel<<<dim3(2, 8, 8), dim3(256), 0, stream>>>(Wk_m, 64, 16384, WmT + 64 * 256, 256, 49152);
    tconv_kernel<<<dim3(2, 8, 8), dim3(256), 0, stream>>>(Wv_m, 64, 16384, WmT + 128 * 256, 256, 49152);
    fcg_prep<<<dim3(128), dim3(256), 0, stream>>>(fc_m_w, gate_m_w, fcgT);
    // ---- Phase B: mask path (fp32) + folded weight product ----
    gemm_nn<<<dim3(1, 64, 1), dim3(256), 0, stream>>>(
        inp, Wk_i + 512 * 64, krow, 4096, 64, 512, 512, 64, 64, 0, 0, 0);
    gemm_nn<<<dim3(1, 64, 8), dim3(256), 0, stream>>>(
        hx, Wq_i, qbuf, 4096, 64, 256, 2048, 64, 512, 256, 16384, 64);
    s1_mask_kernel<<<dim3(1024), dim3(256), 0, stream>>>(qbuf, krow, a_buf, maskb);
    // WvFT(1024x512) = fcT(1024x1024) @ WvB(512x1024)^T
    gemm_mfma_obf16<<<dim3(8, 8, 1), dim3(256), 0, stream>>>(
        fcT, 1024, WvB, 1024, WvFT, 512, 1024);
    // wfcb(4096x1024) = inpb(4096x512) @ WvFT^T
    gemm_mfma_obf16<<<dim3(16, 32, 1), dim3(256), 0, stream>>>(
        inpb, 512, WvFT, 512, wfcb, 1024, 512);
    // ---- Phase C: fused MFMA GEMM + GRU -> hnewb ----
    gru_fused_mfma<<<dim3(2048), dim3(256), 0, stream>>>(
        wfcb, hxb, a_buf, cbuf, Wihb, Whhb, bhh, hnewb);
    // ---- Phase D: q/k/v_m projections (bf16, into hx_out region) ----
    gemm_mfma_qkv<<<dim3(3, 32, 8), dim3(256), 0, stream>>>(hnewb, WmT, qkvb);
    // ---- Phase E: memory attention + att GEMM + final ----
    mattn_kernel<<<dim3(512), dim3(256), 0, stream>>>(
        qkvb, qkvb + 2097152, qkvb + 4194304, omb);
    att_gemm<<<dim3(8, 256, 1), dim3(256), 0, stream>>>(omb, fcgT, fc_m_b, gate_m_b, attb);
    final_elem<<<dim3(8192), dim3(256), 0, stream>>>(
        hnewb, attb, maskb, hx, cx, hx_out, cx_out, mask_w);
}

// Round 7
// 286.119 us; speedup vs baseline: 5.5776x; 1.0170x over previous
//
#include <hip/hip_runtime.h>
#include <hip/hip_bf16.h>

#define B_SZ 4096
#define NHID_ 2048

typedef __bf16 bf16x8 __attribute__((ext_vector_type(8)));
typedef float f32x4 __attribute__((ext_vector_type(4)));

__device__ __forceinline__ float sigmoidf_(float x) { return 1.f / (1.f + expf(-x)); }
__device__ __forceinline__ float b2f_(unsigned short u) {
    unsigned v = (unsigned)u << 16;
    return __builtin_bit_cast(float, v);
}

#define GLDS16(gp, lp) __builtin_amdgcn_global_load_lds( \
    (const __attribute__((address_space(1))) void*)(gp), \
    (__attribute__((address_space(3))) void*)(lp), 16, 0, 0)

// ---------------------------------------------------------------------------
// fp32 -> bf16 conversion, 4 elems/thread, grid-stride
// ---------------------------------------------------------------------------
__global__ __launch_bounds__(256) void f2b_kernel(
    const float* __restrict__ src, __hip_bfloat16* __restrict__ dst, long n4)
{
    long i = (long)blockIdx.x * 256 + threadIdx.x;
    const long stride = (long)gridDim.x * 256;
    for (; i < n4; i += stride) {
        float4 v = ((const float4*)src)[i];
        __hip_bfloat16 b0 = __float2bfloat16(v.x);
        __hip_bfloat16 b1 = __float2bfloat16(v.y);
        __hip_bfloat16 b2 = __float2bfloat16(v.z);
        __hip_bfloat16 b3 = __float2bfloat16(v.w);
        ushort4 u;
        u.x = *(unsigned short*)&b0; u.y = *(unsigned short*)&b1;
        u.z = *(unsigned short*)&b2; u.w = *(unsigned short*)&b3;
        ((ushort4*)dst)[i] = u;
    }
}

// ---------------------------------------------------------------------------
// Wih convert + cb: Wihb = bf16(Wih); cb[j] = dot(fc_i_b, Wih[j,:]) + bih[j]
// ---------------------------------------------------------------------------
__global__ __launch_bounds__(256) void wih_prep(
    const float* __restrict__ Wih, const float* __restrict__ fc_i_b,
    const float* __restrict__ bih, __hip_bfloat16* __restrict__ Wihb,
    float* __restrict__ cb)
{
    long j = blockIdx.x;
    const float* row = Wih + j * 1024;
    __hip_bfloat16* drow = Wihb + j * 1024;
    int i = threadIdx.x * 4;
    float4 v = *(const float4*)(row + i);
    __hip_bfloat16 b0 = __float2bfloat16(v.x);
    __hip_bfloat16 b1 = __float2bfloat16(v.y);
    __hip_bfloat16 b2 = __float2bfloat16(v.z);
    __hip_bfloat16 b3 = __float2bfloat16(v.w);
    ushort4 u;
    u.x = *(unsigned short*)&b0; u.y = *(unsigned short*)&b1;
    u.z = *(unsigned short*)&b2; u.w = *(unsigned short*)&b3;
    *(ushort4*)(drow + i) = u;
    float s = fc_i_b[i] * v.x + fc_i_b[i + 1] * v.y +
              fc_i_b[i + 2] * v.z + fc_i_b[i + 3] * v.w;
#pragma unroll
    for (int off = 32; off > 0; off >>= 1) s += __shfl_xor(s, off, 64);
    __shared__ float red[4];
    if ((threadIdx.x & 63) == 0) red[threadIdx.x >> 6] = s;
    __syncthreads();
    if (threadIdx.x == 0) cb[j] = red[0] + red[1] + red[2] + red[3] + bih[j];
}

// ---------------------------------------------------------------------------
// Transpose + convert: dst[c*ldd + r] (bf16) = src[r*C + c] (f32), batched z.
// ---------------------------------------------------------------------------
__global__ __launch_bounds__(256) void tconv_kernel(
    const float* __restrict__ src, int C, long sS,
    __hip_bfloat16* __restrict__ dst, int ldd, long sD)
{
    src += (long)blockIdx.z * sS;
    dst += (long)blockIdx.z * sD;
    const int r0 = blockIdx.y * 32, c0 = blockIdx.x * 32;
    const int tx = threadIdx.x & 31, ty = threadIdx.x >> 5;
    __shared__ float tile[32][33];
#pragma unroll
    for (int i = 0; i < 4; ++i)
        tile[ty + i * 8][tx] = src[(long)(r0 + ty + i * 8) * C + c0 + tx];
    __syncthreads();
#pragma unroll
    for (int i = 0; i < 4; ++i)
        dst[(long)(c0 + ty + i * 8) * ldd + r0 + tx] = __float2bfloat16(tile[tx][ty + i * 8]);
}

// ---------------------------------------------------------------------------
// Build fcgT (512 x 64)
// ---------------------------------------------------------------------------
__global__ __launch_bounds__(256) void fcg_prep(
    const float* __restrict__ fc_w, const float* __restrict__ gate_w,
    __hip_bfloat16* __restrict__ fcgT)
{
    int tid = blockIdx.x * 256 + threadIdx.x;  // 32768
    int np = tid >> 6, k = tid & 63;
    int o = (np >> 5) * 16 + (np & 15);
    const float* src = ((np >> 4) & 1) ? gate_w : fc_w;
    fcgT[tid] = __float2bfloat16(src[k * 256 + o]);
}

// ---------------------------------------------------------------------------
// Generic fp32 tiled GEMM (mask-precision-critical helpers only)
// ---------------------------------------------------------------------------
#define GM_BM 64
#define GM_BN 64
#define GM_BK 16

__global__ __launch_bounds__(256) void gemm_nn(
    const float* __restrict__ A, const float* __restrict__ Bm, float* __restrict__ C,
    int M, int N, int K, int lda, int ldb, int ldc,
    long sA, long sB, long sC)
{
    const int z = blockIdx.z;
    A += (long)z * sA; Bm += (long)z * sB; C += (long)z * sC;
    const int m0 = blockIdx.y * GM_BM;
    const int n0 = blockIdx.x * GM_BN;
    const int tid = threadIdx.x;
    const int tx = tid & 15;
    const int ty = tid >> 4;

    __shared__ float As[GM_BK][GM_BM + 4];
    __shared__ float Bs[GM_BK][GM_BN + 4];

    float acc[4][4] = {};

    for (int k0 = 0; k0 < K; k0 += GM_BK) {
#pragma unroll
        for (int i = 0; i < 4; ++i) {
            int idx = tid + i * 256;
            int r = idx >> 4, c = idx & 15;
            As[c][r] = A[(long)(m0 + r) * lda + k0 + c];
        }
#pragma unroll
        for (int i = 0; i < 4; ++i) {
            int idx = tid + i * 256;
            int r = idx >> 6, c = idx & 63;
            Bs[r][c] = Bm[(long)(k0 + r) * ldb + n0 + c];
        }
        __syncthreads();
#pragma unroll
        for (int kk = 0; kk < GM_BK; ++kk) {
            float4 a4 = *(const float4*)&As[kk][ty * 4];
            float4 b4 = *(const float4*)&Bs[kk][tx * 4];
            float av[4] = {a4.x, a4.y, a4.z, a4.w};
            float bv[4] = {b4.x, b4.y, b4.z, b4.w};
#pragma unroll
            for (int i = 0; i < 4; ++i)
#pragma unroll
                for (int j = 0; j < 4; ++j)
                    acc[i][j] += av[i] * bv[j];
        }
        __syncthreads();
    }
#pragma unroll
    for (int i = 0; i < 4; ++i) {
        long m = m0 + ty * 4 + i;
#pragma unroll
        for (int j = 0; j < 4; ++j) {
            int n = n0 + tx * 4 + j;
            C[m * ldc + n] = acc[i][j];
        }
    }
}

// ---------------------------------------------------------------------------
// MFMA GEMM: C(bf16, MxN) = A(bf16, MxK, lda) @ BT(bf16, NxK, ldb)^T
// ---------------------------------------------------------------------------
__global__ __launch_bounds__(256) void gemm_mfma_obf16(
    const __hip_bfloat16* __restrict__ A, int lda,
    const __hip_bfloat16* __restrict__ BT, int ldb,
    __hip_bfloat16* __restrict__ C, int ldc, int K)
{
    const int m0 = blockIdx.y * 128;
    const int n0 = blockIdx.x * 64;
    const int tid = threadIdx.x;
    const int lane = tid & 63, wid = tid >> 6;
    const int wr = wid >> 1, wc = wid & 1;
    const int l15 = lane & 15, l4 = lane >> 4;

    __shared__ __align__(16) char lds_raw[16384 + 8192];
    char* Alds = lds_raw;
    char* Blds = lds_raw + 16384;

    f32x4 acc[4][2] = {};

    for (int k0 = 0; k0 < K; k0 += 64) {
#pragma unroll
        for (int ii = 0; ii < 4; ++ii) {
            int issue = ii * 4 + wid;
            int chunk = issue * 64 + lane;
            int r = chunk >> 3, cs = chunk & 7;
            int cl = cs ^ (r & 7);
            const __hip_bfloat16* g = A + (long)(m0 + r) * lda + k0 + cl * 8;
            GLDS16(g, Alds + issue * 1024);
        }
#pragma unroll
        for (int jj = 0; jj < 2; ++jj) {
            int issue = jj * 4 + wid;
            int chunk = issue * 64 + lane;
            int r = chunk >> 3, cs = chunk & 7;
            int cl = cs ^ (r & 7);
            const __hip_bfloat16* g = BT + (long)(n0 + r) * ldb + k0 + cl * 8;
            GLDS16(g, Blds + issue * 1024);
        }
        __syncthreads();
#pragma unroll
        for (int kk = 0; kk < 2; ++kk) {
            bf16x8 af[4], bfr[2];
#pragma unroll
            for (int im = 0; im < 4; ++im) {
                int r = wr * 64 + im * 16 + l15;
                int cl = (kk * 4 + l4) ^ (l15 & 7);
                af[im] = *(const bf16x8*)(Alds + r * 128 + cl * 16);
            }
#pragma unroll
            for (int jn = 0; jn < 2; ++jn) {
                int r = wc * 32 + jn * 16 + l15;
                int cl = (kk * 4 + l4) ^ (l15 & 7);
                bfr[jn] = *(const bf16x8*)(Blds + r * 128 + cl * 16);
            }
#pragma unroll
            for (int im = 0; im < 4; ++im)
#pragma unroll
                for (int jn = 0; jn < 2; ++jn)
                    acc[im][jn] = __builtin_amdgcn_mfma_f32_16x16x32_bf16(
                        af[im], bfr[jn], acc[im][jn], 0, 0, 0);
        }
        __syncthreads();
    }
#pragma unroll
    for (int im = 0; im < 4; ++im)
#pragma unroll
        for (int reg = 0; reg < 4; ++reg) {
            long m = m0 + wr * 64 + im * 16 + l4 * 4 + reg;
#pragma unroll
            for (int jn = 0; jn < 2; ++jn) {
                int n = n0 + wc * 32 + jn * 16 + l15;
                C[m * ldc + n] = __float2bfloat16(acc[im][jn][reg]);
            }
        }
}

// ---------------------------------------------------------------------------
// Fused q/k/v_m projections (bf16 out).
// ---------------------------------------------------------------------------
__global__ __launch_bounds__(256) void gemm_mfma_qkv(
    const __hip_bfloat16* __restrict__ hnewb,  // (B,2048)
    const __hip_bfloat16* __restrict__ WmT,    // (8,192,256)
    __hip_bfloat16* __restrict__ qout)         // q|k|v, each 2097152 bf16
{
    const int z = blockIdx.z;
    const int m0 = blockIdx.y * 128;
    const int n0 = blockIdx.x * 64;
    const int tid = threadIdx.x;
    const int lane = tid & 63, wid = tid >> 6;
    const int wr = wid >> 1, wc = wid & 1;
    const int l15 = lane & 15, l4 = lane >> 4;

    const __hip_bfloat16* A = hnewb + z * 256;
    const __hip_bfloat16* BT = WmT + (long)z * 192 * 256;

    __shared__ __align__(16) char lds_raw[16384 + 8192];
    char* Alds = lds_raw;
    char* Blds = lds_raw + 16384;

    f32x4 acc[4][2] = {};

    for (int k0 = 0; k0 < 256; k0 += 64) {
#pragma unroll
        for (int ii = 0; ii < 4; ++ii) {
            int issue = ii * 4 + wid;
            int chunk = issue * 64 + lane;
            int r = chunk >> 3, cs = chunk & 7;
            int cl = cs ^ (r & 7);
            const __hip_bfloat16* g = A + (long)(m0 + r) * 2048 + k0 + cl * 8;
            GLDS16(g, Alds + issue * 1024);
        }
#pragma unroll
        for (int jj = 0; jj < 2; ++jj) {
            int issue = jj * 4 + wid;
            int chunk = issue * 64 + lane;
            int r = chunk >> 3, cs = chunk & 7;
            int cl = cs ^ (r & 7);
            const __hip_bfloat16* g = BT + (long)(n0 + r) * 256 + k0 + cl * 8;
            GLDS16(g, Blds + issue * 1024);
        }
        __syncthreads();
#pragma unroll
        for (int kk = 0; kk < 2; ++kk) {
            bf16x8 af[4], bfr[2];
#pragma unroll
            for (int im = 0; im < 4; ++im) {
                int r = wr * 64 + im * 16 + l15;
                int cl = (kk * 4 + l4) ^ (l15 & 7);
                af[im] = *(const bf16x8*)(Alds + r * 128 + cl * 16);
            }
#pragma unroll
            for (int jn = 0; jn < 2; ++jn) {
                int r = wc * 32 + jn * 16 + l15;
                int cl = (kk * 4 + l4) ^ (l15 & 7);
                bfr[jn] = *(const bf16x8*)(Blds + r * 128 + cl * 16);
            }
#pragma unroll
            for (int im = 0; im < 4; ++im)
#pragma unroll
                for (int jn = 0; jn < 2; ++jn)
                    acc[im][jn] = __builtin_amdgcn_mfma_f32_16x16x32_bf16(
                        af[im], bfr[jn], acc[im][jn], 0, 0, 0);
        }
        __syncthreads();
    }
#pragma unroll
    for (int jn = 0; jn < 2; ++jn) {
        int j = n0 + wc * 32 + jn * 16 + l15;   // [0,192)
        int g = j >> 6, d = j & 63;
        __hip_bfloat16* outp = qout + (long)g * 2097152 + (long)z * 64 + d;
#pragma unroll
        for (int im = 0; im < 4; ++im)
#pragma unroll
            for (int reg = 0; reg < 4; ++reg) {
                long m = m0 + wr * 64 + im * 16 + l4 * 4 + reg;
                outp[m * 512] = __float2bfloat16(acc[im][jn][reg]);
            }
    }
}

// ---------------------------------------------------------------------------
// s1 / sigmoid(s1) / top-k mask (fp32 — rank decisions are precision-critical)
// ---------------------------------------------------------------------------
__global__ __launch_bounds__(256) void s1_mask_kernel(
    const float* __restrict__ qbuf, const float* __restrict__ krow,
    float* __restrict__ a_buf, float* __restrict__ mask_buf)
{
    const int wave = threadIdx.x >> 6;
    const int lane = threadIdx.x & 63;
    const long b = (long)blockIdx.x * 4 + wave;
    const float kr = krow[b * 64 + lane];
    float s1v[8];
#pragma unroll
    for (int n = 0; n < 8; ++n) {
        float p = qbuf[b * 512 + n * 64 + lane] * kr;
#pragma unroll
        for (int off = 32; off > 0; off >>= 1) p += __shfl_xor(p, off, 64);
        s1v[n] = p * 0.125f;
    }
    unsigned maskbits = 0;
#pragma unroll
    for (int n = 0; n < 8; ++n) {
        int rank = 0;
#pragma unroll
        for (int m = 0; m < 8; ++m) {
            if (m == n) continue;
            if (s1v[m] < s1v[n] || (s1v[m] == s1v[n] && m < n)) rank++;
        }
        if (rank >= 4) maskbits |= (1u << n);
    }
    if (lane < 8) {
        float sv = s1v[0];
#pragma unroll
        for (int n = 1; n < 8; ++n)
            if (lane == n) sv = s1v[n];
        a_buf[b * 8 + lane] = sigmoidf_(sv);
        mask_buf[b * 8 + lane] = ((maskbits >> lane) & 1u) ? 1.0f : 0.0f;
    }
}

// ---------------------------------------------------------------------------
// MFMA big GEMM + fused GRU epilogue. 512 threads / 8 waves (wave = 32m x 48n),
// same 128m x 96n block tile & 2-barrier structure; XCD-pinned kblk = bid&7.
// 8-wave split halves per-wave acc VGPRs (96->48) to lift occupancy 2->4 w/SIMD.
// ---------------------------------------------------------------------------
__global__ __launch_bounds__(512) void gru_fused_mfma(
    const __hip_bfloat16* __restrict__ wfcb,   // (B,1024)
    const __hip_bfloat16* __restrict__ hxb,    // (B,2048)
    const float* __restrict__ a_buf,           // (B,8)
    const float* __restrict__ cb,              // (8,768)
    const __hip_bfloat16* __restrict__ Wihb,   // (8,768,1024)
    const __hip_bfloat16* __restrict__ Whhb,   // (8,768,256)
    const float* __restrict__ bhh,             // (8,768)
    __hip_bfloat16* __restrict__ hnewb)        // (B,2048)
{
    const int bid = blockIdx.x;
    const int kblk = bid & 7;
    const int r_ = bid >> 3;
    const int ol0 = (r_ & 7) * 32;
    const int m0 = (r_ >> 3) * 128;
    const int tid = threadIdx.x;
    const int lane = tid & 63, wid = tid >> 6;   // wid 0..7
    const int wr = wid >> 1;                     // 0..3 : 32-row group
    const int wc = wid & 1;                      // 0..1 : 16-ol group
    const int l15 = lane & 15, l4 = lane >> 4;

    __shared__ __align__(16) char lds_raw[16384 + 12288];
    char* Alds = lds_raw;
    char* Blds = lds_raw + 16384;

    f32x4 accx[2][3] = {};
    f32x4 acch[2][3] = {};

#define STAGE(Asrc, sA, Bsrc, sB, k0) do {                                     \
    for (int ii = wid; ii < 16; ii += 8) {                                     \
        int chunk = ii * 64 + lane;                                            \
        int r = chunk >> 3, cs = chunk & 7;                                    \
        int cl = cs ^ (r & 7);                                                 \
        const __hip_bfloat16* g = (Asrc) + (long)(m0 + r) * (sA) + (k0) + cl * 8; \
        GLDS16(g, Alds + ii * 1024);                                           \
    }                                                                          \
    for (int jj = wid; jj < 12; jj += 8) {                                     \
        int chunk = jj * 64 + lane;                                            \
        int r = chunk >> 3, cs = chunk & 7;                                    \
        int cl = cs ^ (r & 7);                                                 \
        int gg = r >> 5, oll = r & 31;                                         \
        const __hip_bfloat16* g = (Bsrc) + (long)(gg * 256 + ol0 + oll) * (sB) + (k0) + cl * 8; \
        GLDS16(g, Blds + jj * 1024);                                           \
    }                                                                          \
} while (0)

#define COMPUTE(acc) do {                                                      \
    _Pragma("unroll") for (int kk = 0; kk < 2; ++kk) {                         \
        bf16x8 af[2], bfr[3];                                                  \
        _Pragma("unroll") for (int im = 0; im < 2; ++im) {                     \
            int r = wr * 32 + im * 16 + l15;                                   \
            int cl = (kk * 4 + l4) ^ (l15 & 7);                                \
            af[im] = *(const bf16x8*)(Alds + r * 128 + cl * 16);               \
        }                                                                      \
        _Pragma("unroll") for (int g = 0; g < 3; ++g) {                        \
            int r = g * 32 + wc * 16 + l15;                                    \
            int cl = (kk * 4 + l4) ^ (l15 & 7);                                \
            bfr[g] = *(const bf16x8*)(Blds + r * 128 + cl * 16);               \
        }                                                                      \
        _Pragma("unroll") for (int im = 0; im < 2; ++im)                       \
            _Pragma("unroll") for (int g = 0; g < 3; ++g)                      \
                acc[im][g] = __builtin_amdgcn_mfma_f32_16x16x32_bf16(          \
                    af[im], bfr[g], acc[im][g], 0, 0, 0);                      \
    }                                                                          \
} while (0)

    const __hip_bfloat16* Wk = Wihb + (long)kblk * 768 * 1024;
    for (int k0 = 0; k0 < 1024; k0 += 64) {
        STAGE(wfcb, 1024, Wk, 1024, k0);
        __syncthreads();
        COMPUTE(accx);
        __syncthreads();
    }
    const __hip_bfloat16* Wh = Whhb + (long)kblk * 768 * 256;
    const __hip_bfloat16* hxk = hxb + kblk * 256;
    for (int k0 = 0; k0 < 256; k0 += 64) {
        STAGE(hxk, 2048, Wh, 256, k0);
        __syncthreads();
        COMPUTE(acch);
        __syncthreads();
    }
#undef STAGE
#undef COMPUTE

    const int ol = ol0 + wc * 16 + l15;
    const float* cbk = cb + kblk * 768;
    const float cb0 = cbk[ol], cb1 = cbk[256 + ol], cb2 = cbk[512 + ol];
    const float* bhk = bhh + kblk * 768;
    const float bh0 = bhk[ol], bh1 = bhk[256 + ol], bh2 = bhk[512 + ol];
#pragma unroll
    for (int im = 0; im < 2; ++im) {
#pragma unroll
        for (int reg = 0; reg < 4; ++reg) {
            long m = m0 + wr * 32 + im * 16 + l4 * 4 + reg;
            float av = a_buf[m * 8 + kblk];
            float gx0 = av * accx[im][0][reg] + cb0;
            float gx1 = av * accx[im][1][reg] + cb1;
            float gx2 = av * accx[im][2][reg] + cb2;
            float gh0 = acch[im][0][reg] + bh0;
            float gh1 = acch[im][1][reg] + bh1;
            float gh2 = acch[im][2][reg] + bh2;
            float rr = sigmoidf_(gx0 + gh0);
            float zz = sigmoidf_(gx1 + gh1);
            float nn = tanhf(gx2 + rr * gh2);
            long idx = m * 2048 + kblk * 256 + ol;
            float hxv = __bfloat162float(hxb[idx]);
            hnewb[idx] = __float2bfloat16((1.f - zz) * nn + zz * hxv);
        }
    }
}

// ---------------------------------------------------------------------------
// Memory attention (bf16 in/out)
// ---------------------------------------------------------------------------
__global__ __launch_bounds__(256) void mattn_kernel(
    const __hip_bfloat16* __restrict__ qm, const __hip_bfloat16* __restrict__ km,
    const __hip_bfloat16* __restrict__ vm, __hip_bfloat16* __restrict__ omb)
{
    const int t = threadIdx.x;
    const int local = t & 31;
    const long b = (long)blockIdx.x * 8 + (t >> 5);
    const int h = local >> 3, qn = local & 7;
    const long base = b * 512 + h * 16;

    float qv[16];
#pragma unroll
    for (int i = 0; i < 2; ++i) {
        bf16x8 v = *(const bf16x8*)(qm + base + qn * 64 + i * 8);
#pragma unroll
        for (int j = 0; j < 8; ++j) qv[i * 8 + j] = (float)v[j];
    }
    float sc[8];
#pragma unroll
    for (int kn = 0; kn < 8; ++kn) {
        float s = 0.f;
#pragma unroll
        for (int i = 0; i < 2; ++i) {
            bf16x8 v = *(const bf16x8*)(km + base + kn * 64 + i * 8);
#pragma unroll
            for (int j = 0; j < 8; ++j) s += qv[i * 8 + j] * (float)v[j];
        }
        sc[kn] = s * 0.25f;
    }
    float mx = sc[0];
#pragma unroll
    for (int kn = 1; kn < 8; ++kn) mx = fmaxf(mx, sc[kn]);
    float ssum = 0.f;
#pragma unroll
    for (int kn = 0; kn < 8; ++kn) { sc[kn] = expf(sc[kn] - mx); ssum += sc[kn]; }
    float inv = 1.f / ssum;

    float acc[16] = {};
#pragma unroll
    for (int kn = 0; kn < 8; ++kn) {
        float w = sc[kn] * inv;
#pragma unroll
        for (int i = 0; i < 2; ++i) {
            bf16x8 v = *(const bf16x8*)(vm + base + kn * 64 + i * 8);
#pragma unroll
            for (int j = 0; j < 8; ++j) acc[i * 8 + j] += w * (float)v[j];
        }
    }
#pragma unroll
    for (int i = 0; i < 2; ++i) {
        bf16x8 o;
#pragma unroll
        for (int j = 0; j < 8; ++j) o[j] = (__bf16)acc[i * 8 + j];
        *(bf16x8*)(omb + base + qn * 64 + i * 8) = o;
    }
}

// ---------------------------------------------------------------------------
// att GEMM: (32768 x 64) om @ fcgT(512x64)^T with fused sig*tanh epilogue.
// ---------------------------------------------------------------------------
__global__ __launch_bounds__(256) void att_gemm(
    const __hip_bfloat16* __restrict__ omb,    // (32768,64)
    const __hip_bfloat16* __restrict__ fcgT,   // (512,64)
    const float* __restrict__ fc_b, const float* __restrict__ gate_b,
    __hip_bfloat16* __restrict__ attb)         // (32768,256) == (B,2048)
{
    const int m0 = blockIdx.y * 128;
    const int n0 = blockIdx.x * 64;
    const int tid = threadIdx.x;
    const int lane = tid & 63, wid = tid >> 6;
    const int wr = wid >> 1, wc = wid & 1;
    const int l15 = lane & 15, l4 = lane >> 4;

    __shared__ __align__(16) char lds_raw[16384 + 8192];
    char* Alds = lds_raw;
    char* Blds = lds_raw + 16384;

    f32x4 acc[4][2] = {};
#pragma unroll
    for (int ii = 0; ii < 4; ++ii) {
        int issue = ii * 4 + wid;
        int chunk = issue * 64 + lane;
        int r = chunk >> 3, cs = chunk & 7;
        int cl = cs ^ (r & 7);
        const __hip_bfloat16* g = omb + (long)(m0 + r) * 64 + cl * 8;
        GLDS16(g, Alds + issue * 1024);
    }
#pragma unroll
    for (int jj = 0; jj < 2; ++jj) {
        int issue = jj * 4 + wid;
        int chunk = issue * 64 + lane;
        int r = chunk >> 3, cs = chunk & 7;
        int cl = cs ^ (r & 7);
        const __hip_bfloat16* g = fcgT + (long)(n0 + r) * 64 + cl * 8;
        GLDS16(g, Blds + issue * 1024);
    }
    __syncthreads();
#pragma unroll
    for (int kk = 0; kk < 2; ++kk) {
        bf16x8 af[4], bfr[2];
#pragma unroll
        for (int im = 0; im < 4; ++im) {
            int r = wr * 64 + im * 16 + l15;
            int cl = (kk * 4 + l4) ^ (l15 & 7);
            af[im] = *(const bf16x8*)(Alds + r * 128 + cl * 16);
        }
#pragma unroll
        for (int jn = 0; jn < 2; ++jn) {
            int r = wc * 32 + jn * 16 + l15;
            int cl = (kk * 4 + l4) ^ (l15 & 7);
            bfr[jn] = *(const bf16x8*)(Blds + r * 128 + cl * 16);
        }
#pragma unroll
        for (int im = 0; im < 4; ++im)
#pragma unroll
            for (int jn = 0; jn < 2; ++jn)
                acc[im][jn] = __builtin_amdgcn_mfma_f32_16x16x32_bf16(
                    af[im], bfr[jn], acc[im][jn], 0, 0, 0);
    }
    const int o = ((n0 + wc * 32) >> 1) + l15;
    const float fb = fc_b[o], gb = gate_b[o];
#pragma unroll
    for (int im = 0; im < 4; ++im)
#pragma unroll
        for (int reg = 0; reg < 4; ++reg) {
            long m = m0 + wr * 64 + im * 16 + l4 * 4 + reg;
            float att = sigmoidf_(acc[im][1][reg] + gb) * tanhf(acc[im][0][reg] + fb);
            attb[m * 256 + o] = __float2bfloat16(att);
        }
}

// ---------------------------------------------------------------------------
// Final elementwise: h2 = hnewb + attb; masked select; mask_w write.
// ---------------------------------------------------------------------------
__global__ __launch_bounds__(256) void final_elem(
    const __hip_bfloat16* __restrict__ hnewb, const __hip_bfloat16* __restrict__ attb,
    const float* __restrict__ maskb,
    const float* __restrict__ hx, const float* __restrict__ cx,
    float* __restrict__ hx_out, float* __restrict__ cx_out, float* __restrict__ mask_w)
{
    long i4 = (long)blockIdx.x * 256 + threadIdx.x;   // 2,097,152 quads
    long e = i4 * 4;
    int n = (int)((e >> 8) & 7);
    long b = e >> 11;
    float mv = maskb[b * 8 + n];
    ushort4 hn = ((const ushort4*)hnewb)[i4];
    ushort4 at = ((const ushort4*)attb)[i4];
    float4 hxv = ((const float4*)hx)[i4];
    float4 cxv = ((const float4*)cx)[i4];
    float4 h2;
    h2.x = b2f_(hn.x) + b2f_(at.x);
    h2.y = b2f_(hn.y) + b2f_(at.y);
    h2.z = b2f_(hn.z) + b2f_(at.z);
    h2.w = b2f_(hn.w) + b2f_(at.w);
    bool k = (mv != 0.f);
    float4 ho = k ? h2 : hxv;
    float4 co = k ? h2 : cxv;
    ((float4*)hx_out)[i4] = ho;
    ((float4*)cx_out)[i4] = co;
    ((float4*)mask_w)[i4] = make_float4(mv, mv, mv, mv);
}

// ---------------------------------------------------------------------------
extern "C" void kernel_launch(void* const* d_in, const int* in_sizes, int n_in,
                              void* d_out, int out_size, void* d_ws, size_t ws_size,
                              hipStream_t stream)
{
    const float* inp     = (const float*)d_in[0];
    const float* hx      = (const float*)d_in[1];
    const float* cx      = (const float*)d_in[2];
    const float* Wq_i    = (const float*)d_in[4];
    const float* Wk_i    = (const float*)d_in[5];
    const float* Wv_i    = (const float*)d_in[6];
    const float* fc_i_w  = (const float*)d_in[7];
    const float* fc_i_b  = (const float*)d_in[8];
    const float* Wq_m    = (const float*)d_in[9];
    const float* Wk_m    = (const float*)d_in[10];
    const float* Wv_m    = (const float*)d_in[11];
    const float* fc_m_w  = (const float*)d_in[12];
    const float* fc_m_b  = (const float*)d_in[13];
    const float* gate_m_w= (const float*)d_in[14];
    const float* gate_m_b= (const float*)d_in[15];
    const float* Wih     = (const float*)d_in[16];
    const float* Whh     = (const float*)d_in[17];
    const float* bih     = (const float*)d_in[18];
    const float* bhh     = (const float*)d_in[19];

    float* out = (float*)d_out;
    const long BH = (long)B_SZ * NHID_;   // 8388608
    float* hx_out = out;
    float* cx_out = out + BH;
    float* mask_w = out + 2 * BH;
    __hip_bfloat16* hxb = (__hip_bfloat16*)out;   // bf16 hx in hx_out region (dead after gru)
    __hip_bfloat16* qkvb = (__hip_bfloat16*)out;  // q|k|v bf16, written post-gru

    // Workspace layout (float offsets; all sizes exact):
    float* w = (float*)d_ws;
    float* a_buf = w;                                        // [0, 32768)
    float* maskb = w + 32768;                                // [32768, 65536)
    float* cbuf  = w + 65536;                                // [65536, 71680)
    __hip_bfloat16* fcgT = (__hip_bfloat16*)(w + 73728);     // 32768 bf16   -> [73728, 90112)
    __hip_bfloat16* WmT  = (__hip_bfloat16*)(w + 90112);     // 393216 bf16  -> [90112, 286720)
    __hip_bfloat16* Wihb = (__hip_bfloat16*)(w + 286720);    // 6291456 bf16 -> [286720, 3432448)
    __hip_bfloat16* Whhb = (__hip_bfloat16*)(w + 3432448);   // 1572864 bf16 -> [3432448, 4218880)
    __hip_bfloat16* wfcb = (__hip_bfloat16*)(w + 4218880);   // 4194304 bf16 -> [4218880, 6316032)
    __hip_bfloat16* hnewb= (__hip_bfloat16*)(w + 6316032);   // 8388608 bf16 -> [6316032, 10510336)
    // pre-gru overlays inside hnewb's region (all dead before gru writes hnewb):
    float* qbuf = w + 6316032;                               // [6316032, 8413184)
    float* krow = w + 8413184;                               // [8413184, 8675328)
    __hip_bfloat16* inpb = (__hip_bfloat16*)(w + 8675328);   // 2097152 bf16 -> [8675328, 9723904)
    __hip_bfloat16* WvB  = (__hip_bfloat16*)(w + 9723904);   // 524288 bf16  -> [9723904, 9986048)
    __hip_bfloat16* fcT  = (__hip_bfloat16*)(w + 9986048);   // 1048576 bf16 -> [9986048, 10510336)
    __hip_bfloat16* WvFT = (__hip_bfloat16*)(w + 10510336);  // 524288 bf16  -> [10510336, 10772480)
    // post-gru overlays (Wihb/Whhb/wfcb dead):
    __hip_bfloat16* omb  = (__hip_bfloat16*)(w + 286720);    // 2097152 bf16 -> [286720, 1335296)
    __hip_bfloat16* attb = (__hip_bfloat16*)(w + 1335296);   // 8388608 bf16 -> [1335296, 5529600)

    // ---- Phase A: conversions / prep ----
    wih_prep<<<dim3(6144), dim3(256), 0, stream>>>(Wih, fc_i_b, bih, Wihb, cbuf);
    f2b_kernel<<<dim3(2048), dim3(256), 0, stream>>>(hx, hxb, 2097152);
    f2b_kernel<<<dim3(1024), dim3(256), 0, stream>>>(inp, inpb, 524288);
    f2b_kernel<<<dim3(1024), dim3(256), 0, stream>>>(Whh, Whhb, 393216);
    f2b_kernel<<<dim3(512), dim3(256), 0, stream>>>(Wv_i + 512 * 1024, WvB, 131072);
    tconv_kernel<<<dim3(32, 32, 1), dim3(256), 0, stream>>>(fc_i_w, 1024, 0, fcT, 1024, 0);
    tconv_kernel<<<dim3(2, 8, 8), dim3(256), 0, stream>>>(Wq_m, 64, 16384, WmT, 256, 49152);
    tconv_kernel<<<dim3(2, 8, 8), dim3(256), 0, stream>>>(Wk_m, 64, 16384, WmT + 64 * 256, 256, 49152);
    tconv_kernel<<<dim3(2, 8, 8), dim3(256), 0, stream>>>(Wv_m, 64, 16384, WmT + 128 * 256, 256, 49152);
    fcg_prep<<<dim3(128), dim3(256), 0, stream>>>(fc_m_w, gate_m_w, fcgT);
    // ---- Phase B: mask path (fp32) + folded weight product ----
    gemm_nn<<<dim3(1, 64, 1), dim3(256), 0, stream>>>(
        inp, Wk_i + 512 * 64, krow, 4096, 64, 512, 512, 64, 64, 0, 0, 0);
    gemm_nn<<<dim3(1, 64, 8), dim3(256), 0, stream>>>(
        hx, Wq_i, qbuf, 4096, 64, 256, 2048, 64, 512, 256, 16384, 64);
    s1_mask_kernel<<<dim3(1024), dim3(256), 0, stream>>>(qbuf, krow, a_buf, maskb);
    // WvFT(1024x512) = fcT(1024x1024) @ WvB(512x1024)^T
    gemm_mfma_obf16<<<dim3(8, 8, 1), dim3(256), 0, stream>>>(
        fcT, 1024, WvB, 1024, WvFT, 512, 1024);
    // wfcb(4096x1024) = inpb(4096x512) @ WvFT^T
    gemm_mfma_obf16<<<dim3(16, 32, 1), dim3(256), 0, stream>>>(
        inpb, 512, WvFT, 512, wfcb, 1024, 512);
    // ---- Phase C: fused MFMA GEMM + GRU -> hnewb (512-thread / 8-wave) ----
    gru_fused_mfma<<<dim3(2048), dim3(512), 0, stream>>>(
        wfcb, hxb, a_buf, cbuf, Wihb, Whhb, bhh, hnewb);
    // ---- Phase D: q/k/v_m projections (bf16, into hx_out region) ----
    gemm_mfma_qkv<<<dim3(3, 32, 8), dim3(256), 0, stream>>>(hnewb, WmT, qkvb);
    // ---- Phase E: memory attention + att GEMM + final ----
    mattn_kernel<<<dim3(512), dim3(256), 0, stream>>>(
        qkvb, qkvb + 2097152, qkvb + 4194304, omb);
    att_gemm<<<dim3(8, 256, 1), dim3(256), 0, stream>>>(omb, fcgT, fc_m_b, gate_m_b, attb);
    final_elem<<<dim3(8192), dim3(256), 0, stream>>>(
        hnewb, attb, maskb, hx, cx, hx_out, cx_out, mask_w);
}